// Round 2
// baseline (725.612 us; speedup 1.0000x reference)
//
#include <hip/hip_runtime.h>

#define NN 100000   // nodes
#define EE 1600000  // edges
#define BQ 65536    // queries
#define NBK 391     // node buckets of 256 (ceil(NN/256))
#define BINB 256    // binning grid: 256 blocks keeps >=128B runs per (block,bucket)
#define ECH 6250    // edges per binning block (EE/BINB)
#define DBIN 64     // degree bins for load-balanced aggregation (clamp at 63)

typedef __attribute__((ext_vector_type(8))) short short8;
typedef __attribute__((ext_vector_type(4))) float f32x4;
typedef __attribute__((ext_vector_type(2))) float f32x2;

__device__ __forceinline__ unsigned short bf16_rn(float f) {
    unsigned u = __builtin_bit_cast(unsigned, f);
    u += 0x7fff + ((u >> 16) & 1);
    return (unsigned short)(u >> 16);
}

// ---------------- fp8 e4m3 helpers (HW cvt with SW fallback) ------------------------

#if defined(__has_builtin)
#if __has_builtin(__builtin_amdgcn_cvt_pk_fp8_f32) && __has_builtin(__builtin_amdgcn_cvt_pk_f32_fp8)
#define HW_FP8 1
#endif
#endif
#ifndef HW_FP8
#define HW_FP8 0
#endif

__device__ __forceinline__ unsigned char sw_f32_to_e4m3(float f) {
    float a = fabsf(f);
    unsigned s = __builtin_bit_cast(unsigned, f) >> 31;
    if (!(a < 448.f)) return (unsigned char)((s << 7) | 0x7E);
    if (a < 0.015625f) {
        int q = (int)rintf(a * 512.0f);
        return (unsigned char)((s << 7) | q);
    }
    int e; float m = frexpf(a, &e);
    int q = (int)rintf(m * 16.0f);
    int exp = e - 1 + 7;
    if (q == 16) { q = 8; exp++; }
    if (exp >= 16 || (exp == 15 && q == 15)) return (unsigned char)((s << 7) | 0x7E);
    return (unsigned char)((s << 7) | (exp << 3) | (q - 8));
}
__device__ __forceinline__ float sw_e4m3_to_f32(unsigned char v) {
    unsigned s = v >> 7, e = (v >> 3) & 15, m = v & 7;
    float r = e ? ldexpf((float)(8 + m), (int)e - 10) : ldexpf((float)m, -9);
    return s ? -r : r;
}

__device__ __forceinline__ unsigned char f32_to_e4m3b(float f) {
#if HW_FP8
    return (unsigned char)(__builtin_amdgcn_cvt_pk_fp8_f32(f, f, 0, false) & 0xFF);
#else
    return sw_f32_to_e4m3(f);
#endif
}
__device__ __forceinline__ void unpack4_e4m3(unsigned v, float* o) {
#if HW_FP8
    f32x2 lo = __builtin_amdgcn_cvt_pk_f32_fp8((int)v, false);
    f32x2 hi = __builtin_amdgcn_cvt_pk_f32_fp8((int)v, true);
    o[0] = lo[0]; o[1] = lo[1]; o[2] = hi[0]; o[3] = hi[1];
#else
    o[0] = sw_e4m3_to_f32(v & 0xFF);
    o[1] = sw_e4m3_to_f32((v >> 8) & 0xFF);
    o[2] = sw_e4m3_to_f32((v >> 16) & 0xFF);
    o[3] = sw_e4m3_to_f32((v >> 24) & 0xFF);
#endif
}
// 8 fp8 -> 8 bf16 (exact)
__device__ __forceinline__ short8 fp8x8_to_bf16x8(uint2 u) {
    float f[8];
    unpack4_e4m3(u.x, f);
    unpack4_e4m3(u.y, f + 4);
    union { unsigned short s[8]; short8 v; } o;
#pragma unroll
    for (int i = 0; i < 8; i++) o.s[i] = bf16_rn(f[i]);
    return o.v;
}

// ---------------- bucket count / scan / bin / offsets / place -----------------------

__global__ __launch_bounds__(1024) void k_bcount(const int* __restrict__ dst,
                                                 int* __restrict__ bcnt) {
    __shared__ int h[NBK];
    int t = threadIdx.x, b = blockIdx.x;
    for (int j = t; j < NBK; j += 1024) h[j] = 0;
    __syncthreads();
    int lo = b * ECH, hi = lo + ECH;
    for (int i = lo + t; i < hi; i += 1024) atomicAdd(&h[dst[i] >> 8], 1);
    __syncthreads();
    for (int j = t; j < NBK; j += 1024)
        if (h[j]) atomicAdd(&bcnt[j], h[j]);
}

__global__ __launch_bounds__(512) void k_bscan(const int* __restrict__ bcnt,
                                               int* __restrict__ bbase,
                                               int* __restrict__ bcur) {
    __shared__ int sd[512];
    int t = threadIdx.x;
    int v = (t < NBK) ? bcnt[t] : 0;
    sd[t] = v;
    __syncthreads();
    for (int o = 1; o < 512; o <<= 1) {
        int x = (t >= o) ? sd[t - o] : 0;
        __syncthreads();
        sd[t] += x;
        __syncthreads();
    }
    if (t < NBK) { int e = sd[t] - v; bbase[t] = e; bcur[t] = e; }
    if (t == 0) bbase[NBK] = EE;
}

__global__ __launch_bounds__(1024) void k_bin(const int* __restrict__ src,
                                              const int* __restrict__ dst,
                                              int* __restrict__ bcur,
                                              int2* __restrict__ binned) {
    __shared__ int h[NBK];
    __shared__ int cur[NBK];
    int t = threadIdx.x, b = blockIdx.x;
    for (int j = t; j < NBK; j += 1024) { h[j] = 0; cur[j] = 0; }
    __syncthreads();
    int lo = b * ECH, hi = lo + ECH;
    for (int i = lo + t; i < hi; i += 1024) atomicAdd(&h[dst[i] >> 8], 1);
    __syncthreads();
    for (int j = t; j < NBK; j += 1024)
        if (h[j]) h[j] = atomicAdd(&bcur[j], h[j]);
    __syncthreads();
    for (int i = lo + t; i < hi; i += 1024) {
        int d = dst[i], bk = d >> 8;
        int pos = h[bk] + atomicAdd(&cur[bk], 1);
        binned[pos] = make_int2(src[i], d);
    }
}

// also builds the degree histogram used for load-balanced aggregation
__global__ __launch_bounds__(256) void k_boff(const int2* __restrict__ binned,
                                              const int* __restrict__ bbase,
                                              int* __restrict__ offsets,
                                              float* __restrict__ dinv,
                                              int* __restrict__ dhist) {
    __shared__ int lh[256];
    __shared__ int sd[256];
    int t = threadIdx.x, b = blockIdx.x;
    lh[t] = 0;
    __syncthreads();
    int lo = bbase[b], hi = bbase[b + 1];
    for (int i = lo + t; i < hi; i += 256) atomicAdd(&lh[binned[i].y & 255], 1);
    __syncthreads();
    int v = lh[t];
    sd[t] = v;
    __syncthreads();
    for (int o = 1; o < 256; o <<= 1) {
        int x = (t >= o) ? sd[t - o] : 0;
        __syncthreads();
        sd[t] += x;
        __syncthreads();
    }
    int node = (b << 8) + t;
    if (node < NN) {
        offsets[node] = lo + (sd[t] - v);
        dinv[node] = rsqrtf((float)v + 1.0f);
        atomicAdd(&dhist[v < DBIN ? v : DBIN - 1], 1);
    }
    if (b == NBK - 1 && t == 0) offsets[NN] = EE;
}

__global__ __launch_bounds__(256) void k_place(const int2* __restrict__ binned,
                                               const int* __restrict__ bbase,
                                               const int* __restrict__ offsets,
                                               const float* __restrict__ dinv,
                                               int2* __restrict__ epair) {
    __shared__ int lcur[256];
    int t = threadIdx.x, b = blockIdx.x;
    int node = (b << 8) + t;
    lcur[t] = (node < NN) ? offsets[node] : 0;
    __syncthreads();
    int lo = bbase[b], hi = bbase[b + 1];
    for (int i = lo + t; i < hi; i += 256) {
        int2 e = binned[i];
        int pos = atomicAdd(&lcur[e.y & 255], 1);
        epair[pos] = make_int2(e.x, __builtin_bit_cast(int, dinv[e.x]));
    }
}

// ---------------- degree-sorted node permutation (counting sort, k_bin pattern) -----
// Waves of k_agg8 then own 8 equal-degree nodes -> no trip-count divergence.

__global__ __launch_bounds__(256) void k_dperm(const int* __restrict__ offsets,
                                               const int* __restrict__ dhist,
                                               int* __restrict__ dcur,
                                               int* __restrict__ perm) {
    __shared__ int base[DBIN];
    __shared__ int lh[DBIN];
    __shared__ int lcur[DBIN];
    int t = threadIdx.x;
    if (t < DBIN) {
        int v = dhist[t], s = v;
#pragma unroll
        for (int o = 1; o < DBIN; o <<= 1) {
            int x = __shfl_up(s, o);
            if (t >= o) s += x;
        }
        base[t] = s - v;   // exclusive prefix
        lh[t] = 0;
        lcur[t] = 0;
    }
    __syncthreads();
    int node = blockIdx.x * 256 + t;
    int bin = -1;
    if (node < NN) {
        int deg = offsets[node + 1] - offsets[node];
        bin = deg < DBIN ? deg : DBIN - 1;
        atomicAdd(&lh[bin], 1);
    }
    __syncthreads();
    if (t < DBIN && lh[t]) lh[t] = atomicAdd(&dcur[t], lh[t]);
    __syncthreads();
    if (node < NN) {
        int pos = base[bin] + lh[bin] + atomicAdd(&lcur[bin], 1);
        perm[pos] = node;
    }
}

// ---------------- fused weight convert + CC table (independent, one launch) ---------

__global__ __launch_bounds__(256) void k_wtcc(const float* __restrict__ W1,
                                              const float* __restrict__ W2,
                                              const float* __restrict__ W3,
                                              const float* __restrict__ Wf,
                                              const float* __restrict__ Wh1,
                                              const float* __restrict__ Wh2,
                                              const float* __restrict__ Wh3,
                                              unsigned short* __restrict__ Wt1,
                                              unsigned short* __restrict__ Wt2,
                                              unsigned short* __restrict__ Wt3,
                                              unsigned short* __restrict__ Wtf,
                                              unsigned short* __restrict__ Wth1,
                                              unsigned short* __restrict__ Wth2,
                                              unsigned short* __restrict__ Wth3,
                                              const float* __restrict__ day_table,
                                              const float* __restrict__ time_table,
                                              const float* __restrict__ mode_table,
                                              const float* __restrict__ bf,
                                              const float* __restrict__ bh1,
                                              float* __restrict__ CC) {
    if (blockIdx.x < 672) {
        int i = blockIdx.x * 256 + threadIdx.x;
        const float* W; unsigned short* Wt; int K, N, idx;
        if (i < 16384)       { W = W1;  Wt = Wt1;  K = 128; N = 128; idx = i; }
        else if (i < 32768)  { W = W2;  Wt = Wt2;  K = 128; N = 128; idx = i - 16384; }
        else if (i < 49152)  { W = W3;  Wt = Wt3;  K = 128; N = 128; idx = i - 32768; }
        else if (i < 65536)  { W = Wf;  Wt = Wtf;  K = 128; N = 128; idx = i - 49152; }
        else if (i < 131072) { W = Wh1; Wt = Wth1; K = 256; N = 256; idx = i - 65536; }
        else if (i < 163840) { W = Wh2; Wt = Wth2; K = 256; N = 128; idx = i - 131072; }
        else if (i < 172032) { W = Wh3; Wt = Wth3; K = 128; N = 64;  idx = i - 163840; }
        else return;
        int k = idx / N, n = idx % N;
        Wt[(size_t)n * K + k] = bf16_rn(W[idx]);
    } else {
        int c = blockIdx.x - 672;             // 0..29
        int mode = c % 3, dt = c / 3, time = dt % 5, day = dt / 5;
        __shared__ float temp[128];
        int t = threadIdx.x;
        if (t < 128) {
            float s = bf[t];
            for (int j = 0; j < 64; j++) s = fmaf(day_table[day * 64 + j],  Wf[j * 128 + t], s);
            for (int j = 0; j < 64; j++) s = fmaf(time_table[time * 64 + j], Wf[(64 + j) * 128 + t], s);
            temp[t] = fmaxf(s, 0.f);
        }
        __syncthreads();
        float s = bh1[t];
        for (int k = 0; k < 128; k++) s = fmaf(temp[k], Wh1[(size_t)(256 + k) * 256 + t], s);
        for (int j = 0; j < 64; j++)  s = fmaf(mode_table[mode * 64 + j], Wh1[(size_t)(384 + j) * 256 + t], s);
        CC[c * 256 + t] = s;
    }
}

// ---------------- bf16 MFMA GEMM: C = A @ Wt^T (+bias)(+relu) -----------------------
// OUTM: 0=f32, 1=bf16, 2=fp8-e4m3. AMODE: 0=bf16, 1=f32, 2=fp8.

template <int K, int BN, int TN, int ACT, int OUTM, int AMODE>
__global__ __launch_bounds__(256) void k_mfma(const void* __restrict__ Ap,
                                              const unsigned short* __restrict__ Wt,
                                              const float* __restrict__ bias,
                                              void* __restrict__ Cp,
                                              int M, int Ntot) {
    constexpr int TM = 4;
    __shared__ unsigned short Al[128][72];
    __shared__ unsigned short Bl[BN][72];
    const int t = threadIdx.x;
    const int lane = t & 63, wave = t >> 6;
    const int ln = lane & 15, q8 = (lane >> 4) * 8;
    const int row0 = blockIdx.x * 128;
    const int col0 = blockIdx.y * BN;
    const int wm0 = (wave >> 1) * 64;
    const int wn0 = (wave & 1) * (TN * 16);
    f32x4 acc[TM][TN];
#pragma unroll
    for (int i = 0; i < TM; i++)
#pragma unroll
        for (int j = 0; j < TN; j++) acc[i][j] = (f32x4){0.f, 0.f, 0.f, 0.f};

    for (int k0 = 0; k0 < K; k0 += 64) {
#pragma unroll
        for (int it = 0; it < 4; it++) {
            int c = it * 256 + t;
            int r = c >> 3, cc = (c & 7) * 8;
            int grow = row0 + r;
            if (AMODE == 1) {
                const float* A = (const float*)Ap;
                union { unsigned short u[8]; short8 v; } tm8;
                if (grow < M) {
                    float4 v0 = *(const float4*)&A[(size_t)grow * K + k0 + cc];
                    float4 v1 = *(const float4*)&A[(size_t)grow * K + k0 + cc + 4];
                    tm8.u[0] = bf16_rn(v0.x); tm8.u[1] = bf16_rn(v0.y);
                    tm8.u[2] = bf16_rn(v0.z); tm8.u[3] = bf16_rn(v0.w);
                    tm8.u[4] = bf16_rn(v1.x); tm8.u[5] = bf16_rn(v1.y);
                    tm8.u[6] = bf16_rn(v1.z); tm8.u[7] = bf16_rn(v1.w);
                } else {
                    tm8.v = (short8){0, 0, 0, 0, 0, 0, 0, 0};
                }
                *(short8*)&Al[r][cc] = tm8.v;
            } else if (AMODE == 2) {
                const unsigned char* A = (const unsigned char*)Ap;
                short8 v = (short8){0, 0, 0, 0, 0, 0, 0, 0};
                if (grow < M) {
                    uint2 u = *(const uint2*)&A[(size_t)grow * K + k0 + cc];
                    v = fp8x8_to_bf16x8(u);
                }
                *(short8*)&Al[r][cc] = v;
            } else {
                const unsigned short* A = (const unsigned short*)Ap;
                short8 v = (short8){0, 0, 0, 0, 0, 0, 0, 0};
                if (grow < M) v = *(const short8*)&A[(size_t)grow * K + k0 + cc];
                *(short8*)&Al[r][cc] = v;
            }
        }
#pragma unroll
        for (int it = 0; it < BN / 32; it++) {
            int c = it * 256 + t;
            int r = c >> 3, cc = (c & 7) * 8;
            *(short8*)&Bl[r][cc] = *(const short8*)&Wt[(size_t)(col0 + r) * K + k0 + cc];
        }
        __syncthreads();
#pragma unroll
        for (int ks = 0; ks < 64; ks += 32) {
            short8 af[TM], bfr[TN];
#pragma unroll
            for (int i = 0; i < TM; i++)
                af[i] = *(const short8*)&Al[wm0 + i * 16 + ln][ks + q8];
#pragma unroll
            for (int j = 0; j < TN; j++)
                bfr[j] = *(const short8*)&Bl[wn0 + j * 16 + ln][ks + q8];
#pragma unroll
            for (int i = 0; i < TM; i++)
#pragma unroll
                for (int j = 0; j < TN; j++)
                    acc[i][j] = __builtin_amdgcn_mfma_f32_16x16x32_bf16(af[i], bfr[j], acc[i][j], 0, 0, 0);
        }
        __syncthreads();
    }
    const int qr = (lane >> 4) * 4;
#pragma unroll
    for (int i = 0; i < TM; i++) {
#pragma unroll
        for (int j = 0; j < TN; j++) {
            int col = col0 + wn0 + j * 16 + ln;
            float bv = bias ? bias[col] : 0.f;
#pragma unroll
            for (int r = 0; r < 4; r++) {
                int row = row0 + wm0 + i * 16 + qr + r;
                if (row < M) {
                    float v = acc[i][j][r] + bv;
                    if (ACT) v = fmaxf(v, 0.f);
                    if (OUTM == 1)      ((unsigned short*)Cp)[(size_t)row * Ntot + col] = bf16_rn(v);
                    else if (OUTM == 2) ((unsigned char*)Cp)[(size_t)row * Ntot + col] = f32_to_e4m3b(v);
                    else                ((float*)Cp)[(size_t)row * Ntot + col] = v;
                }
            }
        }
    }
}

// ---------------- edge aggregation (fp8 gather): wave = 8 nodes, 8 lanes/node -------
// Nodes taken through the degree-sorted perm: the 8 nodes of a wave have identical
// degree -> uniform trip count, no masked-lane iterations.

__global__ __launch_bounds__(256) void k_agg8(const unsigned char* __restrict__ hwp,
                                              const int2* __restrict__ epair,
                                              const int* __restrict__ offsets,
                                              const float* __restrict__ dinv,
                                              const float* __restrict__ bias,
                                              const int* __restrict__ perm,
                                              unsigned char* __restrict__ out) {
    const int wid = blockIdx.x * 4 + (threadIdx.x >> 6);
    const int lane = threadIdx.x & 63;
    const int g = lane >> 3, l = lane & 7;
    const int idx = wid * 8 + g;
    if (idx >= NN) return;
    const int node = perm[idx];
    float acc[16];
#pragma unroll
    for (int i = 0; i < 16; i++) acc[i] = 0.f;
    const int beg = offsets[node], end = offsets[node + 1];
    for (int e = beg; e < end; e += 8) {
        int2 p[8];
#pragma unroll
        for (int j = 0; j < 8; j++) {
            int ee = e + j;
            p[j] = epair[(ee < end) ? ee : (end - 1)];
        }
        uint4 v[8];
#pragma unroll
        for (int j = 0; j < 8; j++)
            v[j] = *(const uint4*)&hwp[(size_t)p[j].x * 128 + l * 16];
#pragma unroll
        for (int j = 0; j < 8; j++) {
            float c = (e + j < end) ? __builtin_bit_cast(float, p[j].y) : 0.f;
            float f[16];
            unpack4_e4m3(v[j].x, f + 0);
            unpack4_e4m3(v[j].y, f + 4);
            unpack4_e4m3(v[j].z, f + 8);
            unpack4_e4m3(v[j].w, f + 12);
#pragma unroll
            for (int i = 0; i < 16; i++) acc[i] = fmaf(f[i], c, acc[i]);
        }
    }
    float dd = dinv[node];
    uint4 sv = *(const uint4*)&hwp[(size_t)node * 128 + l * 16];
    float fs[16];
    unpack4_e4m3(sv.x, fs + 0);
    unpack4_e4m3(sv.y, fs + 4);
    unpack4_e4m3(sv.z, fs + 8);
    unpack4_e4m3(sv.w, fs + 12);
    float bb[16];
#pragma unroll
    for (int i = 0; i < 4; i++)
        *(float4*)&bb[4 * i] = *(const float4*)&bias[l * 16 + 4 * i];
    union { unsigned char b[16]; uint4 v; } o;
#pragma unroll
    for (int i = 0; i < 16; i++) {
        float s = fmaf(fs[i], dd, acc[i]);
        float v = fmaf(s, dd, bb[i]);
        o.b[i] = f32_to_e4m3b(fmaxf(v, 0.f));
    }
    *(uint4*)&out[(size_t)node * 128 + l * 16] = o.v;
}

// ---------------- fused head: z1->z2->z3->z4 entirely in one block ------------------

__global__ __launch_bounds__(256) void k_headall(const unsigned char* __restrict__ hb,
                                                 const int* __restrict__ orig,
                                                 const int* __restrict__ dest,
                                                 const int* __restrict__ day_ids,
                                                 const int* __restrict__ time_ids,
                                                 const int* __restrict__ mode_ids,
                                                 const float* __restrict__ CC,
                                                 const unsigned short* __restrict__ Wth1,
                                                 const unsigned short* __restrict__ Wth2,
                                                 const unsigned short* __restrict__ Wth3,
                                                 const float* __restrict__ bh2,
                                                 const float* __restrict__ bh3,
                                                 const float* __restrict__ Wh4,
                                                 const float* __restrict__ bh4,
                                                 float* __restrict__ out) {
    __shared__ __align__(16) char smem[46080];
    __shared__ int io[64], idd[64], cid[64];
    unsigned short (*Al)[72]   = (unsigned short(*)[72])smem;           // 64 x 72
    unsigned short (*Bl)[72]   = (unsigned short(*)[72])(smem + 9216);  // 256 x 72
    unsigned short (*z1s)[264] = (unsigned short(*)[264])smem;          // 64 x 264 (alias)
    unsigned short (*z2s)[136] = (unsigned short(*)[136])smem;          // 64 x 136 (alias)
    const int t = threadIdx.x;
    const int lane = t & 63, wave = t >> 6;
    const int ln = lane & 15, q8 = (lane >> 4) * 8;
    const int qr = (lane >> 4) * 4;
    const int row0 = blockIdx.x * 64;
    if (t < 64) {
        io[t] = orig[row0 + t];
        idd[t] = dest[row0 + t];
        cid[t] = (day_ids[row0 + t] * 5 + time_ids[row0 + t]) * 3 + mode_ids[row0 + t];
    }
    // ---------------- phase A: z1 = relu(gather(h) @ Wth1^T + CC) ----------------
    const int wn0 = wave * 64;
    f32x4 acc[4][4];
#pragma unroll
    for (int i = 0; i < 4; i++)
#pragma unroll
        for (int j = 0; j < 4; j++) acc[i][j] = (f32x4){0.f, 0.f, 0.f, 0.f};
    __syncthreads();

    for (int k0 = 0; k0 < 256; k0 += 64) {
        const int* idsrc = (k0 < 128) ? io : idd;
        const int kb = k0 & 64;
#pragma unroll
        for (int it = 0; it < 2; it++) {
            int c = it * 256 + t;
            int r = c >> 3, cc = (c & 7) * 8;
            uint2 u = *(const uint2*)&hb[(size_t)idsrc[r] * 128 + kb + cc];
            *(short8*)&Al[r][cc] = fp8x8_to_bf16x8(u);
        }
#pragma unroll
        for (int it = 0; it < 8; it++) {
            int c = it * 256 + t;
            int r = c >> 3, cc = (c & 7) * 8;
            *(short8*)&Bl[r][cc] = *(const short8*)&Wth1[(size_t)r * 256 + k0 + cc];
        }
        __syncthreads();
#pragma unroll
        for (int ks = 0; ks < 64; ks += 32) {
            short8 af[4], bfr[4];
#pragma unroll
            for (int i = 0; i < 4; i++)
                af[i] = *(const short8*)&Al[i * 16 + ln][ks + q8];
#pragma unroll
            for (int j = 0; j < 4; j++)
                bfr[j] = *(const short8*)&Bl[wn0 + j * 16 + ln][ks + q8];
#pragma unroll
            for (int i = 0; i < 4; i++)
#pragma unroll
                for (int j = 0; j < 4; j++)
                    acc[i][j] = __builtin_amdgcn_mfma_f32_16x16x32_bf16(af[i], bfr[j], acc[i][j], 0, 0, 0);
        }
        __syncthreads();   // all waves done with Al/Bl -> safe to alias as z1s
    }
    // epilogue A -> z1s (bf16, in LDS)
#pragma unroll
    for (int i = 0; i < 4; i++) {
#pragma unroll
        for (int j = 0; j < 4; j++) {
            int col = wn0 + j * 16 + ln;
#pragma unroll
            for (int r = 0; r < 4; r++) {
                int rl = i * 16 + qr + r;
                float v = acc[i][j][r] + CC[cid[rl] * 256 + col];
                z1s[rl][col] = bf16_rn(fmaxf(v, 0.f));
            }
        }
    }
    __syncthreads();
    // ---------------- phase B: z2 = relu(z1 @ Wth2^T + bh2) ----------------
    const int bcol0 = wave * 32;
    f32x4 acc2[4][2];
#pragma unroll
    for (int i = 0; i < 4; i++)
#pragma unroll
        for (int j = 0; j < 2; j++) acc2[i][j] = (f32x4){0.f, 0.f, 0.f, 0.f};
#pragma unroll
    for (int ks = 0; ks < 256; ks += 32) {
        short8 af[4], bfr[2];
#pragma unroll
        for (int i = 0; i < 4; i++)
            af[i] = *(const short8*)&z1s[i * 16 + ln][ks + q8];
#pragma unroll
        for (int j = 0; j < 2; j++)
            bfr[j] = *(const short8*)&Wth2[(size_t)(bcol0 + j * 16 + ln) * 256 + ks + q8];
#pragma unroll
        for (int i = 0; i < 4; i++)
#pragma unroll
            for (int j = 0; j < 2; j++)
                acc2[i][j] = __builtin_amdgcn_mfma_f32_16x16x32_bf16(af[i], bfr[j], acc2[i][j], 0, 0, 0);
    }
    __syncthreads();   // all waves done reading z1s -> safe to alias as z2s
#pragma unroll
    for (int i = 0; i < 4; i++) {
#pragma unroll
        for (int j = 0; j < 2; j++) {
            int col = bcol0 + j * 16 + ln;
            float bv = bh2[col];
#pragma unroll
            for (int r = 0; r < 4; r++) {
                int row = i * 16 + qr + r;
                z2s[row][col] = bf16_rn(fmaxf(acc2[i][j][r] + bv, 0.f));
            }
        }
    }
    __syncthreads();
    // ---------------- phase C: out = sigmoid(relu(z2 @ Wth3^T + bh3) . Wh4 + bh4) ----
    const int wr0 = wave * 16;
    f32x4 acc3[4];
#pragma unroll
    for (int j = 0; j < 4; j++) acc3[j] = (f32x4){0.f, 0.f, 0.f, 0.f};
#pragma unroll
    for (int ks = 0; ks < 128; ks += 32) {
        short8 af = *(const short8*)&z2s[wr0 + ln][ks + q8];
#pragma unroll
        for (int j = 0; j < 4; j++) {
            short8 bfr = *(const short8*)&Wth3[(size_t)(j * 16 + ln) * 128 + ks + q8];
            acc3[j] = __builtin_amdgcn_mfma_f32_16x16x32_bf16(af, bfr, acc3[j], 0, 0, 0);
        }
    }
    float b3c[4], w4c[4];
#pragma unroll
    for (int j = 0; j < 4; j++) {
        b3c[j] = bh3[j * 16 + ln];
        w4c[j] = Wh4[j * 16 + ln];
    }
    float b4 = bh4[0];
    float part[4];
#pragma unroll
    for (int r = 0; r < 4; r++) {
        float s = 0.f;
#pragma unroll
        for (int j = 0; j < 4; j++)
            s = fmaf(fmaxf(acc3[j][r] + b3c[j], 0.f), w4c[j], s);
        part[r] = s;
    }
#pragma unroll
    for (int r = 0; r < 4; r++) {
        float s = part[r];
        s += __shfl_xor(s, 1); s += __shfl_xor(s, 2);
        s += __shfl_xor(s, 4); s += __shfl_xor(s, 8);
        part[r] = s;
    }
    if (ln == 0) {
#pragma unroll
        for (int r = 0; r < 4; r++)
            out[row0 + wr0 + qr + r] = 1.0f / (1.0f + expf(-(part[r] + b4)));
    }
}

// ---------------- launch ------------------------------------------------------------

extern "C" void kernel_launch(void* const* d_in, const int* in_sizes, int n_in,
                              void* d_out, int out_size, void* d_ws, size_t ws_size,
                              hipStream_t stream) {
    const float* x          = (const float*)d_in[0];
    const int*   eidx       = (const int*)d_in[1];
    const int*   esrc       = eidx;
    const int*   edst       = eidx + EE;
    const int*   origin     = (const int*)d_in[2];
    const int*   destid     = (const int*)d_in[3];
    const int*   day_ids    = (const int*)d_in[4];
    const int*   time_ids   = (const int*)d_in[5];
    const int*   mode_ids   = (const int*)d_in[6];
    const float* W1 = (const float*)d_in[7];   const float* b1 = (const float*)d_in[8];
    const float* W2 = (const float*)d_in[9];   const float* b2 = (const float*)d_in[10];
    const float* W3 = (const float*)d_in[11];  const float* b3 = (const float*)d_in[12];
    const float* day_table  = (const float*)d_in[13];
    const float* time_table = (const float*)d_in[14];
    const float* mode_table = (const float*)d_in[15];
    const float* Wf  = (const float*)d_in[16]; const float* bf  = (const float*)d_in[17];
    const float* Wh1 = (const float*)d_in[18]; const float* bh1 = (const float*)d_in[19];
    const float* Wh2 = (const float*)d_in[20]; const float* bh2 = (const float*)d_in[21];
    const float* Wh3 = (const float*)d_in[22]; const float* bh3 = (const float*)d_in[23];
    const float* Wh4 = (const float*)d_in[24]; const float* bh4 = (const float*)d_in[25];
    float* out = (float*)d_out;

    char* wsb = (char*)d_ws;
    size_t off = 0;
    auto alloc = [&](size_t bytes) -> char* {
        char* p = wsb + off;
        off = (off + bytes + 511) & ~(size_t)511;
        return p;
    };
    // zero-initialized block: bcnt | dhist | dcur (one memset)
    int*   zblk    = (int*)alloc((NBK + 1 + 2 * DBIN) * 4);
    int*   bcnt    = zblk;
    int*   dhist   = zblk + (NBK + 1);
    int*   dcur    = dhist + DBIN;
    int*   bbase   = (int*)alloc((NBK + 1) * 4);
    int*   bcur    = (int*)alloc((NBK + 1) * 4);
    int*   offsets = (int*)alloc((size_t)(NN + 1) * 4);
    float* dinv    = (float*)alloc((size_t)NN * 4);
    int*   perm    = (int*)alloc((size_t)NN * 4);
    int2*  binned  = (int2*)alloc((size_t)EE * 8);
    int2*  epair   = (int2*)alloc((size_t)EE * 8);
    unsigned short* Wt1  = (unsigned short*)alloc(128 * 128 * 2);
    unsigned short* Wt2  = (unsigned short*)alloc(128 * 128 * 2);
    unsigned short* Wt3  = (unsigned short*)alloc(128 * 128 * 2);
    unsigned short* Wtf  = (unsigned short*)alloc(128 * 128 * 2);
    unsigned short* Wth1 = (unsigned short*)alloc(256 * 256 * 2);
    unsigned short* Wth2 = (unsigned short*)alloc(128 * 256 * 2);
    unsigned short* Wth3 = (unsigned short*)alloc(64 * 128 * 2);
    float* CC = (float*)alloc(30 * 256 * 4);
    unsigned char*  bufHW = (unsigned char*)alloc((size_t)NN * 128);   // fp8 hw
    unsigned char*  bufH  = (unsigned char*)alloc((size_t)NN * 128);   // fp8 h

    hipMemsetAsync(zblk, 0, (NBK + 1 + 2 * DBIN) * 4, stream);
    k_bcount<<<BINB, 1024, 0, stream>>>(edst, bcnt);
    k_bscan<<<1, 512, 0, stream>>>(bcnt, bbase, bcur);
    k_bin<<<BINB, 1024, 0, stream>>>(esrc, edst, bcur, binned);
    k_boff<<<NBK, 256, 0, stream>>>(binned, bbase, offsets, dinv, dhist);
    k_dperm<<<NBK, 256, 0, stream>>>(offsets, dhist, dcur, perm);
    k_place<<<NBK, 256, 0, stream>>>(binned, bbase, offsets, dinv, epair);

    k_wtcc<<<672 + 30, 256, 0, stream>>>(W1, W2, W3, Wf, Wh1, Wh2, Wh3,
                                         Wt1, Wt2, Wt3, Wtf, Wth1, Wth2, Wth3,
                                         day_table, time_table, mode_table, bf, bh1, CC);

    const int GB = (NN + 127) / 128;   // 782
    const int AB = (NN + 31) / 32;     // 3125 blocks, 32 nodes/block
    k_mfma<128, 128, 4, 0, 2, 1><<<dim3(GB, 1), 256, 0, stream>>>(x, Wt1, nullptr, bufHW, NN, 128);
    k_agg8<<<AB, 256, 0, stream>>>(bufHW, epair, offsets, dinv, b1, perm, bufH);
    k_mfma<128, 128, 4, 0, 2, 2><<<dim3(GB, 1), 256, 0, stream>>>(bufH, Wt2, nullptr, bufHW, NN, 128);
    k_agg8<<<AB, 256, 0, stream>>>(bufHW, epair, offsets, dinv, b2, perm, bufH);
    k_mfma<128, 128, 4, 0, 2, 2><<<dim3(GB, 1), 256, 0, stream>>>(bufH, Wt3, nullptr, bufHW, NN, 128);
    k_agg8<<<AB, 256, 0, stream>>>(bufHW, epair, offsets, dinv, b3, perm, bufH);
    // final h = bufH (fp8)

    k_headall<<<BQ / 64, 256, 0, stream>>>(bufH, origin, destid, day_ids, time_ids,
                                           mode_ids, CC, Wth1, Wth2, Wth3,
                                           bh2, bh3, Wh4, bh4, out);
}

// Round 3
// 439.981 us; speedup vs baseline: 1.6492x; 1.6492x over previous
//
#include <hip/hip_runtime.h>

#define NN 100000   // nodes
#define EE 1600000  // edges
#define BQ 65536    // queries
#define NBK 391     // node buckets of 256 (ceil(NN/256))
#define BINB 256    // binning grid: 256 blocks keeps >=128B runs per (block,bucket)
#define ECH 6250    // edges per binning block (EE/BINB)
#define DBIN 64     // degree bins for load-balanced aggregation (clamp at 63)

typedef __attribute__((ext_vector_type(8))) short short8;
typedef __attribute__((ext_vector_type(4))) float f32x4;
typedef __attribute__((ext_vector_type(2))) float f32x2;

__device__ __forceinline__ unsigned short bf16_rn(float f) {
    unsigned u = __builtin_bit_cast(unsigned, f);
    u += 0x7fff + ((u >> 16) & 1);
    return (unsigned short)(u >> 16);
}

// ---------------- fp8 e4m3 helpers (HW cvt with SW fallback) ------------------------

#if defined(__has_builtin)
#if __has_builtin(__builtin_amdgcn_cvt_pk_fp8_f32) && __has_builtin(__builtin_amdgcn_cvt_pk_f32_fp8)
#define HW_FP8 1
#endif
#endif
#ifndef HW_FP8
#define HW_FP8 0
#endif

__device__ __forceinline__ unsigned char sw_f32_to_e4m3(float f) {
    float a = fabsf(f);
    unsigned s = __builtin_bit_cast(unsigned, f) >> 31;
    if (!(a < 448.f)) return (unsigned char)((s << 7) | 0x7E);
    if (a < 0.015625f) {
        int q = (int)rintf(a * 512.0f);
        return (unsigned char)((s << 7) | q);
    }
    int e; float m = frexpf(a, &e);
    int q = (int)rintf(m * 16.0f);
    int exp = e - 1 + 7;
    if (q == 16) { q = 8; exp++; }
    if (exp >= 16 || (exp == 15 && q == 15)) return (unsigned char)((s << 7) | 0x7E);
    return (unsigned char)((s << 7) | (exp << 3) | (q - 8));
}
__device__ __forceinline__ float sw_e4m3_to_f32(unsigned char v) {
    unsigned s = v >> 7, e = (v >> 3) & 15, m = v & 7;
    float r = e ? ldexpf((float)(8 + m), (int)e - 10) : ldexpf((float)m, -9);
    return s ? -r : r;
}

__device__ __forceinline__ unsigned char f32_to_e4m3b(float f) {
#if HW_FP8
    return (unsigned char)(__builtin_amdgcn_cvt_pk_fp8_f32(f, f, 0, false) & 0xFF);
#else
    return sw_f32_to_e4m3(f);
#endif
}
__device__ __forceinline__ void unpack4_e4m3(unsigned v, float* o) {
#if HW_FP8
    f32x2 lo = __builtin_amdgcn_cvt_pk_f32_fp8((int)v, false);
    f32x2 hi = __builtin_amdgcn_cvt_pk_f32_fp8((int)v, true);
    o[0] = lo[0]; o[1] = lo[1]; o[2] = hi[0]; o[3] = hi[1];
#else
    o[0] = sw_e4m3_to_f32(v & 0xFF);
    o[1] = sw_e4m3_to_f32((v >> 8) & 0xFF);
    o[2] = sw_e4m3_to_f32((v >> 16) & 0xFF);
    o[3] = sw_e4m3_to_f32((v >> 24) & 0xFF);
#endif
}
// 8 fp8 -> 8 bf16 (exact)
__device__ __forceinline__ short8 fp8x8_to_bf16x8(uint2 u) {
    float f[8];
    unpack4_e4m3(u.x, f);
    unpack4_e4m3(u.y, f + 4);
    union { unsigned short s[8]; short8 v; } o;
#pragma unroll
    for (int i = 0; i < 8; i++) o.s[i] = bf16_rn(f[i]);
    return o.v;
}

// ---------------- bucket count / scan / bin / offsets / place -----------------------

__global__ __launch_bounds__(1024) void k_bcount(const int* __restrict__ dst,
                                                 int* __restrict__ bcnt) {
    __shared__ int h[NBK];
    int t = threadIdx.x, b = blockIdx.x;
    for (int j = t; j < NBK; j += 1024) h[j] = 0;
    __syncthreads();
    int lo = b * ECH, hi = lo + ECH;
    for (int i = lo + t; i < hi; i += 1024) atomicAdd(&h[dst[i] >> 8], 1);
    __syncthreads();
    for (int j = t; j < NBK; j += 1024)
        if (h[j]) atomicAdd(&bcnt[j], h[j]);
}

__global__ __launch_bounds__(512) void k_bscan(const int* __restrict__ bcnt,
                                               int* __restrict__ bbase,
                                               int* __restrict__ bcur) {
    __shared__ int sd[512];
    int t = threadIdx.x;
    int v = (t < NBK) ? bcnt[t] : 0;
    sd[t] = v;
    __syncthreads();
    for (int o = 1; o < 512; o <<= 1) {
        int x = (t >= o) ? sd[t - o] : 0;
        __syncthreads();
        sd[t] += x;
        __syncthreads();
    }
    if (t < NBK) { int e = sd[t] - v; bbase[t] = e; bcur[t] = e; }
    if (t == 0) bbase[NBK] = EE;
}

__global__ __launch_bounds__(1024) void k_bin(const int* __restrict__ src,
                                              const int* __restrict__ dst,
                                              int* __restrict__ bcur,
                                              int2* __restrict__ binned) {
    __shared__ int h[NBK];
    __shared__ int cur[NBK];
    int t = threadIdx.x, b = blockIdx.x;
    for (int j = t; j < NBK; j += 1024) { h[j] = 0; cur[j] = 0; }
    __syncthreads();
    int lo = b * ECH, hi = lo + ECH;
    for (int i = lo + t; i < hi; i += 1024) atomicAdd(&h[dst[i] >> 8], 1);
    __syncthreads();
    for (int j = t; j < NBK; j += 1024)
        if (h[j]) h[j] = atomicAdd(&bcur[j], h[j]);
    __syncthreads();
    for (int i = lo + t; i < hi; i += 1024) {
        int d = dst[i], bk = d >> 8;
        int pos = h[bk] + atomicAdd(&cur[bk], 1);
        binned[pos] = make_int2(src[i], d);
    }
}

// also builds the degree histogram used for load-balanced aggregation.
// R2 lesson: per-node global atomics onto ~20 hot degree bins serialized at L2
// (292us!). Two-level: LDS histogram per block, then <=64 global atomics/block.
__global__ __launch_bounds__(256) void k_boff(const int2* __restrict__ binned,
                                              const int* __restrict__ bbase,
                                              int* __restrict__ offsets,
                                              float* __restrict__ dinv,
                                              int* __restrict__ dhist) {
    __shared__ int lh[256];
    __shared__ int sd[256];
    __shared__ int dh[DBIN];
    int t = threadIdx.x, b = blockIdx.x;
    lh[t] = 0;
    if (t < DBIN) dh[t] = 0;
    __syncthreads();
    int lo = bbase[b], hi = bbase[b + 1];
    for (int i = lo + t; i < hi; i += 256) atomicAdd(&lh[binned[i].y & 255], 1);
    __syncthreads();
    int v = lh[t];
    sd[t] = v;
    __syncthreads();
    for (int o = 1; o < 256; o <<= 1) {
        int x = (t >= o) ? sd[t - o] : 0;
        __syncthreads();
        sd[t] += x;
        __syncthreads();
    }
    int node = (b << 8) + t;
    if (node < NN) {
        offsets[node] = lo + (sd[t] - v);
        dinv[node] = rsqrtf((float)v + 1.0f);
        atomicAdd(&dh[v < DBIN ? v : DBIN - 1], 1);
    }
    __syncthreads();
    if (t < DBIN && dh[t]) atomicAdd(&dhist[t], dh[t]);
    if (b == NBK - 1 && t == 0) offsets[NN] = EE;
}

__global__ __launch_bounds__(256) void k_place(const int2* __restrict__ binned,
                                               const int* __restrict__ bbase,
                                               const int* __restrict__ offsets,
                                               const float* __restrict__ dinv,
                                               int2* __restrict__ epair) {
    __shared__ int lcur[256];
    int t = threadIdx.x, b = blockIdx.x;
    int node = (b << 8) + t;
    lcur[t] = (node < NN) ? offsets[node] : 0;
    __syncthreads();
    int lo = bbase[b], hi = bbase[b + 1];
    for (int i = lo + t; i < hi; i += 256) {
        int2 e = binned[i];
        int pos = atomicAdd(&lcur[e.y & 255], 1);
        epair[pos] = make_int2(e.x, __builtin_bit_cast(int, dinv[e.x]));
    }
}

// ---------------- degree-sorted node permutation (counting sort, k_bin pattern) -----
// Waves of k_agg8 then own 8 equal-degree nodes -> no trip-count divergence.

__global__ __launch_bounds__(256) void k_dperm(const int* __restrict__ offsets,
                                               const int* __restrict__ dhist,
                                               int* __restrict__ dcur,
                                               int* __restrict__ perm) {
    __shared__ int base[DBIN];
    __shared__ int lh[DBIN];
    __shared__ int lcur[DBIN];
    int t = threadIdx.x;
    if (t < DBIN) {
        int v = dhist[t], s = v;
#pragma unroll
        for (int o = 1; o < DBIN; o <<= 1) {
            int x = __shfl_up(s, o);
            if (t >= o) s += x;
        }
        base[t] = s - v;   // exclusive prefix
        lh[t] = 0;
        lcur[t] = 0;
    }
    __syncthreads();
    int node = blockIdx.x * 256 + t;
    int bin = -1;
    if (node < NN) {
        int deg = offsets[node + 1] - offsets[node];
        bin = deg < DBIN ? deg : DBIN - 1;
        atomicAdd(&lh[bin], 1);
    }
    __syncthreads();
    if (t < DBIN && lh[t]) lh[t] = atomicAdd(&dcur[t], lh[t]);
    __syncthreads();
    if (node < NN) {
        int pos = base[bin] + lh[bin] + atomicAdd(&lcur[bin], 1);
        perm[pos] = node;
    }
}

// ---------------- fused weight convert + CC table (independent, one launch) ---------

__global__ __launch_bounds__(256) void k_wtcc(const float* __restrict__ W1,
                                              const float* __restrict__ W2,
                                              const float* __restrict__ W3,
                                              const float* __restrict__ Wf,
                                              const float* __restrict__ Wh1,
                                              const float* __restrict__ Wh2,
                                              const float* __restrict__ Wh3,
                                              unsigned short* __restrict__ Wt1,
                                              unsigned short* __restrict__ Wt2,
                                              unsigned short* __restrict__ Wt3,
                                              unsigned short* __restrict__ Wtf,
                                              unsigned short* __restrict__ Wth1,
                                              unsigned short* __restrict__ Wth2,
                                              unsigned short* __restrict__ Wth3,
                                              const float* __restrict__ day_table,
                                              const float* __restrict__ time_table,
                                              const float* __restrict__ mode_table,
                                              const float* __restrict__ bf,
                                              const float* __restrict__ bh1,
                                              float* __restrict__ CC) {
    if (blockIdx.x < 672) {
        int i = blockIdx.x * 256 + threadIdx.x;
        const float* W; unsigned short* Wt; int K, N, idx;
        if (i < 16384)       { W = W1;  Wt = Wt1;  K = 128; N = 128; idx = i; }
        else if (i < 32768)  { W = W2;  Wt = Wt2;  K = 128; N = 128; idx = i - 16384; }
        else if (i < 49152)  { W = W3;  Wt = Wt3;  K = 128; N = 128; idx = i - 32768; }
        else if (i < 65536)  { W = Wf;  Wt = Wtf;  K = 128; N = 128; idx = i - 49152; }
        else if (i < 131072) { W = Wh1; Wt = Wth1; K = 256; N = 256; idx = i - 65536; }
        else if (i < 163840) { W = Wh2; Wt = Wth2; K = 256; N = 128; idx = i - 131072; }
        else if (i < 172032) { W = Wh3; Wt = Wth3; K = 128; N = 64;  idx = i - 163840; }
        else return;
        int k = idx / N, n = idx % N;
        Wt[(size_t)n * K + k] = bf16_rn(W[idx]);
    } else {
        int c = blockIdx.x - 672;             // 0..29
        int mode = c % 3, dt = c / 3, time = dt % 5, day = dt / 5;
        __shared__ float temp[128];
        int t = threadIdx.x;
        if (t < 128) {
            float s = bf[t];
            for (int j = 0; j < 64; j++) s = fmaf(day_table[day * 64 + j],  Wf[j * 128 + t], s);
            for (int j = 0; j < 64; j++) s = fmaf(time_table[time * 64 + j], Wf[(64 + j) * 128 + t], s);
            temp[t] = fmaxf(s, 0.f);
        }
        __syncthreads();
        float s = bh1[t];
        for (int k = 0; k < 128; k++) s = fmaf(temp[k], Wh1[(size_t)(256 + k) * 256 + t], s);
        for (int j = 0; j < 64; j++)  s = fmaf(mode_table[mode * 64 + j], Wh1[(size_t)(384 + j) * 256 + t], s);
        CC[c * 256 + t] = s;
    }
}

// ---------------- bf16 MFMA GEMM: C = A @ Wt^T (+bias)(+relu) -----------------------
// OUTM: 0=f32, 1=bf16, 2=fp8-e4m3. AMODE: 0=bf16, 1=f32, 2=fp8.

template <int K, int BN, int TN, int ACT, int OUTM, int AMODE>
__global__ __launch_bounds__(256) void k_mfma(const void* __restrict__ Ap,
                                              const unsigned short* __restrict__ Wt,
                                              const float* __restrict__ bias,
                                              void* __restrict__ Cp,
                                              int M, int Ntot) {
    constexpr int TM = 4;
    __shared__ unsigned short Al[128][72];
    __shared__ unsigned short Bl[BN][72];
    const int t = threadIdx.x;
    const int lane = t & 63, wave = t >> 6;
    const int ln = lane & 15, q8 = (lane >> 4) * 8;
    const int row0 = blockIdx.x * 128;
    const int col0 = blockIdx.y * BN;
    const int wm0 = (wave >> 1) * 64;
    const int wn0 = (wave & 1) * (TN * 16);
    f32x4 acc[TM][TN];
#pragma unroll
    for (int i = 0; i < TM; i++)
#pragma unroll
        for (int j = 0; j < TN; j++) acc[i][j] = (f32x4){0.f, 0.f, 0.f, 0.f};

    for (int k0 = 0; k0 < K; k0 += 64) {
#pragma unroll
        for (int it = 0; it < 4; it++) {
            int c = it * 256 + t;
            int r = c >> 3, cc = (c & 7) * 8;
            int grow = row0 + r;
            if (AMODE == 1) {
                const float* A = (const float*)Ap;
                union { unsigned short u[8]; short8 v; } tm8;
                if (grow < M) {
                    float4 v0 = *(const float4*)&A[(size_t)grow * K + k0 + cc];
                    float4 v1 = *(const float4*)&A[(size_t)grow * K + k0 + cc + 4];
                    tm8.u[0] = bf16_rn(v0.x); tm8.u[1] = bf16_rn(v0.y);
                    tm8.u[2] = bf16_rn(v0.z); tm8.u[3] = bf16_rn(v0.w);
                    tm8.u[4] = bf16_rn(v1.x); tm8.u[5] = bf16_rn(v1.y);
                    tm8.u[6] = bf16_rn(v1.z); tm8.u[7] = bf16_rn(v1.w);
                } else {
                    tm8.v = (short8){0, 0, 0, 0, 0, 0, 0, 0};
                }
                *(short8*)&Al[r][cc] = tm8.v;
            } else if (AMODE == 2) {
                const unsigned char* A = (const unsigned char*)Ap;
                short8 v = (short8){0, 0, 0, 0, 0, 0, 0, 0};
                if (grow < M) {
                    uint2 u = *(const uint2*)&A[(size_t)grow * K + k0 + cc];
                    v = fp8x8_to_bf16x8(u);
                }
                *(short8*)&Al[r][cc] = v;
            } else {
                const unsigned short* A = (const unsigned short*)Ap;
                short8 v = (short8){0, 0, 0, 0, 0, 0, 0, 0};
                if (grow < M) v = *(const short8*)&A[(size_t)grow * K + k0 + cc];
                *(short8*)&Al[r][cc] = v;
            }
        }
#pragma unroll
        for (int it = 0; it < BN / 32; it++) {
            int c = it * 256 + t;
            int r = c >> 3, cc = (c & 7) * 8;
            *(short8*)&Bl[r][cc] = *(const short8*)&Wt[(size_t)(col0 + r) * K + k0 + cc];
        }
        __syncthreads();
#pragma unroll
        for (int ks = 0; ks < 64; ks += 32) {
            short8 af[TM], bfr[TN];
#pragma unroll
            for (int i = 0; i < TM; i++)
                af[i] = *(const short8*)&Al[wm0 + i * 16 + ln][ks + q8];
#pragma unroll
            for (int j = 0; j < TN; j++)
                bfr[j] = *(const short8*)&Bl[wn0 + j * 16 + ln][ks + q8];
#pragma unroll
            for (int i = 0; i < TM; i++)
#pragma unroll
                for (int j = 0; j < TN; j++)
                    acc[i][j] = __builtin_amdgcn_mfma_f32_16x16x32_bf16(af[i], bfr[j], acc[i][j], 0, 0, 0);
        }
        __syncthreads();
    }
    const int qr = (lane >> 4) * 4;
#pragma unroll
    for (int i = 0; i < TM; i++) {
#pragma unroll
        for (int j = 0; j < TN; j++) {
            int col = col0 + wn0 + j * 16 + ln;
            float bv = bias ? bias[col] : 0.f;
#pragma unroll
            for (int r = 0; r < 4; r++) {
                int row = row0 + wm0 + i * 16 + qr + r;
                if (row < M) {
                    float v = acc[i][j][r] + bv;
                    if (ACT) v = fmaxf(v, 0.f);
                    if (OUTM == 1)      ((unsigned short*)Cp)[(size_t)row * Ntot + col] = bf16_rn(v);
                    else if (OUTM == 2) ((unsigned char*)Cp)[(size_t)row * Ntot + col] = f32_to_e4m3b(v);
                    else                ((float*)Cp)[(size_t)row * Ntot + col] = v;
                }
            }
        }
    }
}

// ---------------- edge aggregation (fp8 gather): wave = 8 nodes, 8 lanes/node -------
// Nodes taken through the degree-sorted perm: the 8 nodes of a wave have identical
// degree -> uniform trip count, no masked-lane iterations.

__global__ __launch_bounds__(256) void k_agg8(const unsigned char* __restrict__ hwp,
                                              const int2* __restrict__ epair,
                                              const int* __restrict__ offsets,
                                              const float* __restrict__ dinv,
                                              const float* __restrict__ bias,
                                              const int* __restrict__ perm,
                                              unsigned char* __restrict__ out) {
    const int wid = blockIdx.x * 4 + (threadIdx.x >> 6);
    const int lane = threadIdx.x & 63;
    const int g = lane >> 3, l = lane & 7;
    const int idx = wid * 8 + g;
    if (idx >= NN) return;
    const int node = perm[idx];
    float acc[16];
#pragma unroll
    for (int i = 0; i < 16; i++) acc[i] = 0.f;
    const int beg = offsets[node], end = offsets[node + 1];
    for (int e = beg; e < end; e += 8) {
        int2 p[8];
#pragma unroll
        for (int j = 0; j < 8; j++) {
            int ee = e + j;
            p[j] = epair[(ee < end) ? ee : (end - 1)];
        }
        uint4 v[8];
#pragma unroll
        for (int j = 0; j < 8; j++)
            v[j] = *(const uint4*)&hwp[(size_t)p[j].x * 128 + l * 16];
#pragma unroll
        for (int j = 0; j < 8; j++) {
            float c = (e + j < end) ? __builtin_bit_cast(float, p[j].y) : 0.f;
            float f[16];
            unpack4_e4m3(v[j].x, f + 0);
            unpack4_e4m3(v[j].y, f + 4);
            unpack4_e4m3(v[j].z, f + 8);
            unpack4_e4m3(v[j].w, f + 12);
#pragma unroll
            for (int i = 0; i < 16; i++) acc[i] = fmaf(f[i], c, acc[i]);
        }
    }
    float dd = dinv[node];
    uint4 sv = *(const uint4*)&hwp[(size_t)node * 128 + l * 16];
    float fs[16];
    unpack4_e4m3(sv.x, fs + 0);
    unpack4_e4m3(sv.y, fs + 4);
    unpack4_e4m3(sv.z, fs + 8);
    unpack4_e4m3(sv.w, fs + 12);
    float bb[16];
#pragma unroll
    for (int i = 0; i < 4; i++)
        *(float4*)&bb[4 * i] = *(const float4*)&bias[l * 16 + 4 * i];
    union { unsigned char b[16]; uint4 v; } o;
#pragma unroll
    for (int i = 0; i < 16; i++) {
        float s = fmaf(fs[i], dd, acc[i]);
        float v = fmaf(s, dd, bb[i]);
        o.b[i] = f32_to_e4m3b(fmaxf(v, 0.f));
    }
    *(uint4*)&out[(size_t)node * 128 + l * 16] = o.v;
}

// ---------------- fused head: z1->z2->z3->z4 entirely in one block ------------------

__global__ __launch_bounds__(256) void k_headall(const unsigned char* __restrict__ hb,
                                                 const int* __restrict__ orig,
                                                 const int* __restrict__ dest,
                                                 const int* __restrict__ day_ids,
                                                 const int* __restrict__ time_ids,
                                                 const int* __restrict__ mode_ids,
                                                 const float* __restrict__ CC,
                                                 const unsigned short* __restrict__ Wth1,
                                                 const unsigned short* __restrict__ Wth2,
                                                 const unsigned short* __restrict__ Wth3,
                                                 const float* __restrict__ bh2,
                                                 const float* __restrict__ bh3,
                                                 const float* __restrict__ Wh4,
                                                 const float* __restrict__ bh4,
                                                 float* __restrict__ out) {
    __shared__ __align__(16) char smem[46080];
    __shared__ int io[64], idd[64], cid[64];
    unsigned short (*Al)[72]   = (unsigned short(*)[72])smem;           // 64 x 72
    unsigned short (*Bl)[72]   = (unsigned short(*)[72])(smem + 9216);  // 256 x 72
    unsigned short (*z1s)[264] = (unsigned short(*)[264])smem;          // 64 x 264 (alias)
    unsigned short (*z2s)[136] = (unsigned short(*)[136])smem;          // 64 x 136 (alias)
    const int t = threadIdx.x;
    const int lane = t & 63, wave = t >> 6;
    const int ln = lane & 15, q8 = (lane >> 4) * 8;
    const int qr = (lane >> 4) * 4;
    const int row0 = blockIdx.x * 64;
    if (t < 64) {
        io[t] = orig[row0 + t];
        idd[t] = dest[row0 + t];
        cid[t] = (day_ids[row0 + t] * 5 + time_ids[row0 + t]) * 3 + mode_ids[row0 + t];
    }
    // ---------------- phase A: z1 = relu(gather(h) @ Wth1^T + CC) ----------------
    const int wn0 = wave * 64;
    f32x4 acc[4][4];
#pragma unroll
    for (int i = 0; i < 4; i++)
#pragma unroll
        for (int j = 0; j < 4; j++) acc[i][j] = (f32x4){0.f, 0.f, 0.f, 0.f};
    __syncthreads();

    for (int k0 = 0; k0 < 256; k0 += 64) {
        const int* idsrc = (k0 < 128) ? io : idd;
        const int kb = k0 & 64;
#pragma unroll
        for (int it = 0; it < 2; it++) {
            int c = it * 256 + t;
            int r = c >> 3, cc = (c & 7) * 8;
            uint2 u = *(const uint2*)&hb[(size_t)idsrc[r] * 128 + kb + cc];
            *(short8*)&Al[r][cc] = fp8x8_to_bf16x8(u);
        }
#pragma unroll
        for (int it = 0; it < 8; it++) {
            int c = it * 256 + t;
            int r = c >> 3, cc = (c & 7) * 8;
            *(short8*)&Bl[r][cc] = *(const short8*)&Wth1[(size_t)r * 256 + k0 + cc];
        }
        __syncthreads();
#pragma unroll
        for (int ks = 0; ks < 64; ks += 32) {
            short8 af[4], bfr[4];
#pragma unroll
            for (int i = 0; i < 4; i++)
                af[i] = *(const short8*)&Al[i * 16 + ln][ks + q8];
#pragma unroll
            for (int j = 0; j < 4; j++)
                bfr[j] = *(const short8*)&Bl[wn0 + j * 16 + ln][ks + q8];
#pragma unroll
            for (int i = 0; i < 4; i++)
#pragma unroll
                for (int j = 0; j < 4; j++)
                    acc[i][j] = __builtin_amdgcn_mfma_f32_16x16x32_bf16(af[i], bfr[j], acc[i][j], 0, 0, 0);
        }
        __syncthreads();   // all waves done with Al/Bl -> safe to alias as z1s
    }
    // epilogue A -> z1s (bf16, in LDS)
#pragma unroll
    for (int i = 0; i < 4; i++) {
#pragma unroll
        for (int j = 0; j < 4; j++) {
            int col = wn0 + j * 16 + ln;
#pragma unroll
            for (int r = 0; r < 4; r++) {
                int rl = i * 16 + qr + r;
                float v = acc[i][j][r] + CC[cid[rl] * 256 + col];
                z1s[rl][col] = bf16_rn(fmaxf(v, 0.f));
            }
        }
    }
    __syncthreads();
    // ---------------- phase B: z2 = relu(z1 @ Wth2^T + bh2) ----------------
    const int bcol0 = wave * 32;
    f32x4 acc2[4][2];
#pragma unroll
    for (int i = 0; i < 4; i++)
#pragma unroll
        for (int j = 0; j < 2; j++) acc2[i][j] = (f32x4){0.f, 0.f, 0.f, 0.f};
#pragma unroll
    for (int ks = 0; ks < 256; ks += 32) {
        short8 af[4], bfr[2];
#pragma unroll
        for (int i = 0; i < 4; i++)
            af[i] = *(const short8*)&z1s[i * 16 + ln][ks + q8];
#pragma unroll
        for (int j = 0; j < 2; j++)
            bfr[j] = *(const short8*)&Wth2[(size_t)(bcol0 + j * 16 + ln) * 256 + ks + q8];
#pragma unroll
        for (int i = 0; i < 4; i++)
#pragma unroll
            for (int j = 0; j < 2; j++)
                acc2[i][j] = __builtin_amdgcn_mfma_f32_16x16x32_bf16(af[i], bfr[j], acc2[i][j], 0, 0, 0);
    }
    __syncthreads();   // all waves done reading z1s -> safe to alias as z2s
#pragma unroll
    for (int i = 0; i < 4; i++) {
#pragma unroll
        for (int j = 0; j < 2; j++) {
            int col = bcol0 + j * 16 + ln;
            float bv = bh2[col];
#pragma unroll
            for (int r = 0; r < 4; r++) {
                int row = i * 16 + qr + r;
                z2s[row][col] = bf16_rn(fmaxf(acc2[i][j][r] + bv, 0.f));
            }
        }
    }
    __syncthreads();
    // ---------------- phase C: out = sigmoid(relu(z2 @ Wth3^T + bh3) . Wh4 + bh4) ----
    const int wr0 = wave * 16;
    f32x4 acc3[4];
#pragma unroll
    for (int j = 0; j < 4; j++) acc3[j] = (f32x4){0.f, 0.f, 0.f, 0.f};
#pragma unroll
    for (int ks = 0; ks < 128; ks += 32) {
        short8 af = *(const short8*)&z2s[wr0 + ln][ks + q8];
#pragma unroll
        for (int j = 0; j < 4; j++) {
            short8 bfr = *(const short8*)&Wth3[(size_t)(j * 16 + ln) * 128 + ks + q8];
            acc3[j] = __builtin_amdgcn_mfma_f32_16x16x32_bf16(af, bfr, acc3[j], 0, 0, 0);
        }
    }
    float b3c[4], w4c[4];
#pragma unroll
    for (int j = 0; j < 4; j++) {
        b3c[j] = bh3[j * 16 + ln];
        w4c[j] = Wh4[j * 16 + ln];
    }
    float b4 = bh4[0];
    float part[4];
#pragma unroll
    for (int r = 0; r < 4; r++) {
        float s = 0.f;
#pragma unroll
        for (int j = 0; j < 4; j++)
            s = fmaf(fmaxf(acc3[j][r] + b3c[j], 0.f), w4c[j], s);
        part[r] = s;
    }
#pragma unroll
    for (int r = 0; r < 4; r++) {
        float s = part[r];
        s += __shfl_xor(s, 1); s += __shfl_xor(s, 2);
        s += __shfl_xor(s, 4); s += __shfl_xor(s, 8);
        part[r] = s;
    }
    if (ln == 0) {
#pragma unroll
        for (int r = 0; r < 4; r++)
            out[row0 + wr0 + qr + r] = 1.0f / (1.0f + expf(-(part[r] + b4)));
    }
}

// ---------------- launch ------------------------------------------------------------

extern "C" void kernel_launch(void* const* d_in, const int* in_sizes, int n_in,
                              void* d_out, int out_size, void* d_ws, size_t ws_size,
                              hipStream_t stream) {
    const float* x          = (const float*)d_in[0];
    const int*   eidx       = (const int*)d_in[1];
    const int*   esrc       = eidx;
    const int*   edst       = eidx + EE;
    const int*   origin     = (const int*)d_in[2];
    const int*   destid     = (const int*)d_in[3];
    const int*   day_ids    = (const int*)d_in[4];
    const int*   time_ids   = (const int*)d_in[5];
    const int*   mode_ids   = (const int*)d_in[6];
    const float* W1 = (const float*)d_in[7];   const float* b1 = (const float*)d_in[8];
    const float* W2 = (const float*)d_in[9];   const float* b2 = (const float*)d_in[10];
    const float* W3 = (const float*)d_in[11];  const float* b3 = (const float*)d_in[12];
    const float* day_table  = (const float*)d_in[13];
    const float* time_table = (const float*)d_in[14];
    const float* mode_table = (const float*)d_in[15];
    const float* Wf  = (const float*)d_in[16]; const float* bf  = (const float*)d_in[17];
    const float* Wh1 = (const float*)d_in[18]; const float* bh1 = (const float*)d_in[19];
    const float* Wh2 = (const float*)d_in[20]; const float* bh2 = (const float*)d_in[21];
    const float* Wh3 = (const float*)d_in[22]; const float* bh3 = (const float*)d_in[23];
    const float* Wh4 = (const float*)d_in[24]; const float* bh4 = (const float*)d_in[25];
    float* out = (float*)d_out;

    char* wsb = (char*)d_ws;
    size_t off = 0;
    auto alloc = [&](size_t bytes) -> char* {
        char* p = wsb + off;
        off = (off + bytes + 511) & ~(size_t)511;
        return p;
    };
    // zero-initialized block: bcnt | dhist | dcur (one memset)
    int*   zblk    = (int*)alloc((NBK + 1 + 2 * DBIN) * 4);
    int*   bcnt    = zblk;
    int*   dhist   = zblk + (NBK + 1);
    int*   dcur    = dhist + DBIN;
    int*   bbase   = (int*)alloc((NBK + 1) * 4);
    int*   bcur    = (int*)alloc((NBK + 1) * 4);
    int*   offsets = (int*)alloc((size_t)(NN + 1) * 4);
    float* dinv    = (float*)alloc((size_t)NN * 4);
    int*   perm    = (int*)alloc((size_t)NN * 4);
    int2*  binned  = (int2*)alloc((size_t)EE * 8);
    int2*  epair   = (int2*)alloc((size_t)EE * 8);
    unsigned short* Wt1  = (unsigned short*)alloc(128 * 128 * 2);
    unsigned short* Wt2  = (unsigned short*)alloc(128 * 128 * 2);
    unsigned short* Wt3  = (unsigned short*)alloc(128 * 128 * 2);
    unsigned short* Wtf  = (unsigned short*)alloc(128 * 128 * 2);
    unsigned short* Wth1 = (unsigned short*)alloc(256 * 256 * 2);
    unsigned short* Wth2 = (unsigned short*)alloc(128 * 256 * 2);
    unsigned short* Wth3 = (unsigned short*)alloc(64 * 128 * 2);
    float* CC = (float*)alloc(30 * 256 * 4);
    unsigned char*  bufHW = (unsigned char*)alloc((size_t)NN * 128);   // fp8 hw
    unsigned char*  bufH  = (unsigned char*)alloc((size_t)NN * 128);   // fp8 h

    hipMemsetAsync(zblk, 0, (NBK + 1 + 2 * DBIN) * 4, stream);
    k_bcount<<<BINB, 1024, 0, stream>>>(edst, bcnt);
    k_bscan<<<1, 512, 0, stream>>>(bcnt, bbase, bcur);
    k_bin<<<BINB, 1024, 0, stream>>>(esrc, edst, bcur, binned);
    k_boff<<<NBK, 256, 0, stream>>>(binned, bbase, offsets, dinv, dhist);
    k_dperm<<<NBK, 256, 0, stream>>>(offsets, dhist, dcur, perm);
    k_place<<<NBK, 256, 0, stream>>>(binned, bbase, offsets, dinv, epair);

    k_wtcc<<<672 + 30, 256, 0, stream>>>(W1, W2, W3, Wf, Wh1, Wh2, Wh3,
                                         Wt1, Wt2, Wt3, Wtf, Wth1, Wth2, Wth3,
                                         day_table, time_table, mode_table, bf, bh1, CC);

    const int GB = (NN + 127) / 128;   // 782
    const int AB = (NN + 31) / 32;     // 3125 blocks, 32 nodes/block
    k_mfma<128, 128, 4, 0, 2, 1><<<dim3(GB, 1), 256, 0, stream>>>(x, Wt1, nullptr, bufHW, NN, 128);
    k_agg8<<<AB, 256, 0, stream>>>(bufHW, epair, offsets, dinv, b1, perm, bufH);
    k_mfma<128, 128, 4, 0, 2, 2><<<dim3(GB, 1), 256, 0, stream>>>(bufH, Wt2, nullptr, bufHW, NN, 128);
    k_agg8<<<AB, 256, 0, stream>>>(bufHW, epair, offsets, dinv, b2, perm, bufH);
    k_mfma<128, 128, 4, 0, 2, 2><<<dim3(GB, 1), 256, 0, stream>>>(bufH, Wt3, nullptr, bufHW, NN, 128);
    k_agg8<<<AB, 256, 0, stream>>>(bufHW, epair, offsets, dinv, b3, perm, bufH);
    // final h = bufH (fp8)

    k_headall<<<BQ / 64, 256, 0, stream>>>(bufH, origin, destid, day_ids, time_ids,
                                           mode_ids, CC, Wth1, Wth2, Wth3,
                                           bh2, bh3, Wh4, bh4, out);
}

// Round 4
// 431.652 us; speedup vs baseline: 1.6810x; 1.0193x over previous
//
#include <hip/hip_runtime.h>

#define NN 100000   // nodes
#define EE 1600000  // edges
#define BQ 65536    // queries
#define NBK 391     // node buckets of 256 (ceil(NN/256))
#define BINB 256    // binning grid: 256 blocks keeps >=128B runs per (block,bucket)
#define ECH 6250    // edges per binning block (EE/BINB)

typedef __attribute__((ext_vector_type(8))) short short8;
typedef __attribute__((ext_vector_type(4))) float f32x4;
typedef __attribute__((ext_vector_type(2))) float f32x2;

__device__ __forceinline__ unsigned short bf16_rn(float f) {
    unsigned u = __builtin_bit_cast(unsigned, f);
    u += 0x7fff + ((u >> 16) & 1);
    return (unsigned short)(u >> 16);
}

// ---------------- fp8 e4m3 helpers (HW cvt with SW fallback) ------------------------

#if defined(__has_builtin)
#if __has_builtin(__builtin_amdgcn_cvt_pk_fp8_f32) && __has_builtin(__builtin_amdgcn_cvt_pk_f32_fp8)
#define HW_FP8 1
#endif
#endif
#ifndef HW_FP8
#define HW_FP8 0
#endif

__device__ __forceinline__ unsigned char sw_f32_to_e4m3(float f) {
    float a = fabsf(f);
    unsigned s = __builtin_bit_cast(unsigned, f) >> 31;
    if (!(a < 448.f)) return (unsigned char)((s << 7) | 0x7E);
    if (a < 0.015625f) {
        int q = (int)rintf(a * 512.0f);
        return (unsigned char)((s << 7) | q);
    }
    int e; float m = frexpf(a, &e);
    int q = (int)rintf(m * 16.0f);
    int exp = e - 1 + 7;
    if (q == 16) { q = 8; exp++; }
    if (exp >= 16 || (exp == 15 && q == 15)) return (unsigned char)((s << 7) | 0x7E);
    return (unsigned char)((s << 7) | (exp << 3) | (q - 8));
}
__device__ __forceinline__ float sw_e4m3_to_f32(unsigned char v) {
    unsigned s = v >> 7, e = (v >> 3) & 15, m = v & 7;
    float r = e ? ldexpf((float)(8 + m), (int)e - 10) : ldexpf((float)m, -9);
    return s ? -r : r;
}

__device__ __forceinline__ unsigned char f32_to_e4m3b(float f) {
#if HW_FP8
    return (unsigned char)(__builtin_amdgcn_cvt_pk_fp8_f32(f, f, 0, false) & 0xFF);
#else
    return sw_f32_to_e4m3(f);
#endif
}
__device__ __forceinline__ void unpack4_e4m3(unsigned v, float* o) {
#if HW_FP8
    f32x2 lo = __builtin_amdgcn_cvt_pk_f32_fp8((int)v, false);
    f32x2 hi = __builtin_amdgcn_cvt_pk_f32_fp8((int)v, true);
    o[0] = lo[0]; o[1] = lo[1]; o[2] = hi[0]; o[3] = hi[1];
#else
    o[0] = sw_e4m3_to_f32(v & 0xFF);
    o[1] = sw_e4m3_to_f32((v >> 8) & 0xFF);
    o[2] = sw_e4m3_to_f32((v >> 16) & 0xFF);
    o[3] = sw_e4m3_to_f32((v >> 24) & 0xFF);
#endif
}
// 8 fp8 -> 8 bf16 (exact)
__device__ __forceinline__ short8 fp8x8_to_bf16x8(uint2 u) {
    float f[8];
    unpack4_e4m3(u.x, f);
    unpack4_e4m3(u.y, f + 4);
    union { unsigned short s[8]; short8 v; } o;
#pragma unroll
    for (int i = 0; i < 8; i++) o.s[i] = bf16_rn(f[i]);
    return o.v;
}

// ---------------- bucket count / bin / offsets+place --------------------------------
// R3 pipeline: bcount -> bin (local scan of bcnt, zero-based cursor) ->
// boffplace (fused offsets + epair placement; binned range is L2-hot between
// the two phases). epair stores src only (4B/edge); agg gathers dinv[src] from
// the L2-resident table, which also removes the cross-block dinv dependency.

__global__ __launch_bounds__(1024) void k_bcount(const int* __restrict__ dst,
                                                 int* __restrict__ bcnt) {
    __shared__ int h[NBK];
    int t = threadIdx.x, b = blockIdx.x;
    for (int j = t; j < NBK; j += 1024) h[j] = 0;
    __syncthreads();
    int lo = b * ECH, hi = lo + ECH;
    for (int i = lo + t; i < hi; i += 1024) atomicAdd(&h[dst[i] >> 8], 1);
    __syncthreads();
    for (int j = t; j < NBK; j += 1024)
        if (h[j]) atomicAdd(&bcnt[j], h[j]);
}

__global__ __launch_bounds__(1024) void k_bin(const int* __restrict__ src,
                                              const int* __restrict__ dst,
                                              const int* __restrict__ bcnt,
                                              int* __restrict__ bcur0,
                                              int2* __restrict__ binned) {
    __shared__ int h[NBK];
    __shared__ int cur[NBK];
    __shared__ int sd[512];
    int t = threadIdx.x, b = blockIdx.x;
    for (int j = t; j < NBK; j += 1024) { h[j] = 0; cur[j] = 0; }
    if (t < 512) sd[t] = (t < NBK) ? bcnt[t] : 0;
    __syncthreads();
    int lo = b * ECH, hi = lo + ECH;
    for (int i = lo + t; i < hi; i += 1024) atomicAdd(&h[dst[i] >> 8], 1);
    // inclusive scan of bcnt in sd (barriers also fence the count atomics)
    for (int o = 1; o < 512; o <<= 1) {
        int x = 0;
        if (t < 512 && t >= o) x = sd[t - o];
        __syncthreads();
        if (t < 512) sd[t] += x;
        __syncthreads();
    }
    for (int j = t; j < NBK; j += 1024)
        if (h[j]) h[j] = (sd[j] - bcnt[j]) + atomicAdd(&bcur0[j], h[j]);
    __syncthreads();
    for (int i = lo + t; i < hi; i += 1024) {
        int d = dst[i], bk = d >> 8;
        int pos = h[bk] + atomicAdd(&cur[bk], 1);
        binned[pos] = make_int2(src[i], d);
    }
}

__global__ __launch_bounds__(256) void k_boffplace(const int2* __restrict__ binned,
                                                   const int* __restrict__ bcnt,
                                                   int* __restrict__ offsets,
                                                   float* __restrict__ dinv,
                                                   int* __restrict__ epsrc) {
    __shared__ int lh[256];
    __shared__ int sd[256];
    int t = threadIdx.x, b = blockIdx.x;
    lh[t] = 0;
    // bucket base = sum bcnt[0..b)
    int part = 0;
    for (int j = t; j < b; j += 256) part += bcnt[j];
    sd[t] = part;
    __syncthreads();
    for (int o = 128; o > 0; o >>= 1) {
        if (t < o) sd[t] += sd[t + o];
        __syncthreads();
    }
    const int lo = sd[0];
    const int hi = lo + bcnt[b];
    __syncthreads();
    // phase 1: per-node counts within this bucket
    for (int i = lo + t; i < hi; i += 256) atomicAdd(&lh[binned[i].y & 255], 1);
    __syncthreads();
    int v = lh[t];
    sd[t] = v;
    __syncthreads();
    for (int o = 1; o < 256; o <<= 1) {
        int x = (t >= o) ? sd[t - o] : 0;
        __syncthreads();
        sd[t] += x;
        __syncthreads();
    }
    int node = (b << 8) + t;
    int myoff = lo + sd[t] - v;
    if (node < NN) {
        offsets[node] = myoff;
        dinv[node] = rsqrtf((float)v + 1.0f);
    }
    if (b == NBK - 1 && t == 0) offsets[NN] = EE;
    __syncthreads();
    // phase 2: place (binned range is L2-hot from phase 1)
    lh[t] = myoff;
    __syncthreads();
    for (int i = lo + t; i < hi; i += 256) {
        int2 e = binned[i];
        int pos = atomicAdd(&lh[e.y & 255], 1);
        epsrc[pos] = e.x;
    }
}

// ---------------- fused weight convert + CC table (independent, one launch) ---------

__global__ __launch_bounds__(256) void k_wtcc(const float* __restrict__ W1,
                                              const float* __restrict__ W2,
                                              const float* __restrict__ W3,
                                              const float* __restrict__ Wf,
                                              const float* __restrict__ Wh1,
                                              const float* __restrict__ Wh2,
                                              const float* __restrict__ Wh3,
                                              unsigned short* __restrict__ Wt1,
                                              unsigned short* __restrict__ Wt2,
                                              unsigned short* __restrict__ Wt3,
                                              unsigned short* __restrict__ Wtf,
                                              unsigned short* __restrict__ Wth1,
                                              unsigned short* __restrict__ Wth2,
                                              unsigned short* __restrict__ Wth3,
                                              const float* __restrict__ day_table,
                                              const float* __restrict__ time_table,
                                              const float* __restrict__ mode_table,
                                              const float* __restrict__ bf,
                                              const float* __restrict__ bh1,
                                              float* __restrict__ CC) {
    if (blockIdx.x < 672) {
        int i = blockIdx.x * 256 + threadIdx.x;
        const float* W; unsigned short* Wt; int K, N, idx;
        if (i < 16384)       { W = W1;  Wt = Wt1;  K = 128; N = 128; idx = i; }
        else if (i < 32768)  { W = W2;  Wt = Wt2;  K = 128; N = 128; idx = i - 16384; }
        else if (i < 49152)  { W = W3;  Wt = Wt3;  K = 128; N = 128; idx = i - 32768; }
        else if (i < 65536)  { W = Wf;  Wt = Wtf;  K = 128; N = 128; idx = i - 49152; }
        else if (i < 131072) { W = Wh1; Wt = Wth1; K = 256; N = 256; idx = i - 65536; }
        else if (i < 163840) { W = Wh2; Wt = Wth2; K = 256; N = 128; idx = i - 131072; }
        else if (i < 172032) { W = Wh3; Wt = Wth3; K = 128; N = 64;  idx = i - 163840; }
        else return;
        int k = idx / N, n = idx % N;
        Wt[(size_t)n * K + k] = bf16_rn(W[idx]);
    } else {
        int c = blockIdx.x - 672;             // 0..29
        int mode = c % 3, dt = c / 3, time = dt % 5, day = dt / 5;
        __shared__ float temp[128];
        int t = threadIdx.x;
        if (t < 128) {
            float s = bf[t];
            for (int j = 0; j < 64; j++) s = fmaf(day_table[day * 64 + j],  Wf[j * 128 + t], s);
            for (int j = 0; j < 64; j++) s = fmaf(time_table[time * 64 + j], Wf[(64 + j) * 128 + t], s);
            temp[t] = fmaxf(s, 0.f);
        }
        __syncthreads();
        float s = bh1[t];
        for (int k = 0; k < 128; k++) s = fmaf(temp[k], Wh1[(size_t)(256 + k) * 256 + t], s);
        for (int j = 0; j < 64; j++)  s = fmaf(mode_table[mode * 64 + j], Wh1[(size_t)(384 + j) * 256 + t], s);
        CC[c * 256 + t] = s;
    }
}

// ---------------- bf16 MFMA GEMM: C = A @ Wt^T (+bias)(+relu) -----------------------
// OUTM: 0=f32, 1=bf16, 2=fp8-e4m3. AMODE: 0=bf16, 1=f32, 2=fp8.

template <int K, int BN, int TN, int ACT, int OUTM, int AMODE>
__global__ __launch_bounds__(256) void k_mfma(const void* __restrict__ Ap,
                                              const unsigned short* __restrict__ Wt,
                                              const float* __restrict__ bias,
                                              void* __restrict__ Cp,
                                              int M, int Ntot) {
    constexpr int TM = 4;
    __shared__ unsigned short Al[128][72];
    __shared__ unsigned short Bl[BN][72];
    const int t = threadIdx.x;
    const int lane = t & 63, wave = t >> 6;
    const int ln = lane & 15, q8 = (lane >> 4) * 8;
    const int row0 = blockIdx.x * 128;
    const int col0 = blockIdx.y * BN;
    const int wm0 = (wave >> 1) * 64;
    const int wn0 = (wave & 1) * (TN * 16);
    f32x4 acc[TM][TN];
#pragma unroll
    for (int i = 0; i < TM; i++)
#pragma unroll
        for (int j = 0; j < TN; j++) acc[i][j] = (f32x4){0.f, 0.f, 0.f, 0.f};

    for (int k0 = 0; k0 < K; k0 += 64) {
#pragma unroll
        for (int it = 0; it < 4; it++) {
            int c = it * 256 + t;
            int r = c >> 3, cc = (c & 7) * 8;
            int grow = row0 + r;
            if (AMODE == 1) {
                const float* A = (const float*)Ap;
                union { unsigned short u[8]; short8 v; } tm8;
                if (grow < M) {
                    float4 v0 = *(const float4*)&A[(size_t)grow * K + k0 + cc];
                    float4 v1 = *(const float4*)&A[(size_t)grow * K + k0 + cc + 4];
                    tm8.u[0] = bf16_rn(v0.x); tm8.u[1] = bf16_rn(v0.y);
                    tm8.u[2] = bf16_rn(v0.z); tm8.u[3] = bf16_rn(v0.w);
                    tm8.u[4] = bf16_rn(v1.x); tm8.u[5] = bf16_rn(v1.y);
                    tm8.u[6] = bf16_rn(v1.z); tm8.u[7] = bf16_rn(v1.w);
                } else {
                    tm8.v = (short8){0, 0, 0, 0, 0, 0, 0, 0};
                }
                *(short8*)&Al[r][cc] = tm8.v;
            } else if (AMODE == 2) {
                const unsigned char* A = (const unsigned char*)Ap;
                short8 v = (short8){0, 0, 0, 0, 0, 0, 0, 0};
                if (grow < M) {
                    uint2 u = *(const uint2*)&A[(size_t)grow * K + k0 + cc];
                    v = fp8x8_to_bf16x8(u);
                }
                *(short8*)&Al[r][cc] = v;
            } else {
                const unsigned short* A = (const unsigned short*)Ap;
                short8 v = (short8){0, 0, 0, 0, 0, 0, 0, 0};
                if (grow < M) v = *(const short8*)&A[(size_t)grow * K + k0 + cc];
                *(short8*)&Al[r][cc] = v;
            }
        }
#pragma unroll
        for (int it = 0; it < BN / 32; it++) {
            int c = it * 256 + t;
            int r = c >> 3, cc = (c & 7) * 8;
            *(short8*)&Bl[r][cc] = *(const short8*)&Wt[(size_t)(col0 + r) * K + k0 + cc];
        }
        __syncthreads();
#pragma unroll
        for (int ks = 0; ks < 64; ks += 32) {
            short8 af[TM], bfr[TN];
#pragma unroll
            for (int i = 0; i < TM; i++)
                af[i] = *(const short8*)&Al[wm0 + i * 16 + ln][ks + q8];
#pragma unroll
            for (int j = 0; j < TN; j++)
                bfr[j] = *(const short8*)&Bl[wn0 + j * 16 + ln][ks + q8];
#pragma unroll
            for (int i = 0; i < TM; i++)
#pragma unroll
                for (int j = 0; j < TN; j++)
                    acc[i][j] = __builtin_amdgcn_mfma_f32_16x16x32_bf16(af[i], bfr[j], acc[i][j], 0, 0, 0);
        }
        __syncthreads();
    }
    const int qr = (lane >> 4) * 4;
#pragma unroll
    for (int i = 0; i < TM; i++) {
#pragma unroll
        for (int j = 0; j < TN; j++) {
            int col = col0 + wn0 + j * 16 + ln;
            float bv = bias ? bias[col] : 0.f;
#pragma unroll
            for (int r = 0; r < 4; r++) {
                int row = row0 + wm0 + i * 16 + qr + r;
                if (row < M) {
                    float v = acc[i][j][r] + bv;
                    if (ACT) v = fmaxf(v, 0.f);
                    if (OUTM == 1)      ((unsigned short*)Cp)[(size_t)row * Ntot + col] = bf16_rn(v);
                    else if (OUTM == 2) ((unsigned char*)Cp)[(size_t)row * Ntot + col] = f32_to_e4m3b(v);
                    else                ((float*)Cp)[(size_t)row * Ntot + col] = v;
                }
            }
        }
    }
}

// ---------------- edge aggregation (fp8 gather): wave = 8 nodes, 8 lanes/node -------
// epsrc is src-only (4B/edge); dinv[src] gathered from the L2-resident table
// (same-address within each 8-lane group -> broadcast, hidden under row gathers).

__global__ __launch_bounds__(256) void k_agg8(const unsigned char* __restrict__ hwp,
                                              const int* __restrict__ epsrc,
                                              const int* __restrict__ offsets,
                                              const float* __restrict__ dinv,
                                              const float* __restrict__ bias,
                                              unsigned char* __restrict__ out) {
    const int wid = blockIdx.x * 4 + (threadIdx.x >> 6);
    const int lane = threadIdx.x & 63;
    const int g = lane >> 3, l = lane & 7;
    const int node = wid * 8 + g;
    if (node >= NN) return;
    float acc[16];
#pragma unroll
    for (int i = 0; i < 16; i++) acc[i] = 0.f;
    const int beg = offsets[node], end = offsets[node + 1];
    for (int e = beg; e < end; e += 8) {
        int p[8];
#pragma unroll
        for (int j = 0; j < 8; j++) {
            int ee = e + j;
            p[j] = epsrc[(ee < end) ? ee : (end - 1)];
        }
        float cdi[8];
#pragma unroll
        for (int j = 0; j < 8; j++) cdi[j] = dinv[p[j]];
        uint4 v[8];
#pragma unroll
        for (int j = 0; j < 8; j++)
            v[j] = *(const uint4*)&hwp[(size_t)p[j] * 128 + l * 16];
#pragma unroll
        for (int j = 0; j < 8; j++) {
            float c = (e + j < end) ? cdi[j] : 0.f;
            float f[16];
            unpack4_e4m3(v[j].x, f + 0);
            unpack4_e4m3(v[j].y, f + 4);
            unpack4_e4m3(v[j].z, f + 8);
            unpack4_e4m3(v[j].w, f + 12);
#pragma unroll
            for (int i = 0; i < 16; i++) acc[i] = fmaf(f[i], c, acc[i]);
        }
    }
    float dd = dinv[node];
    uint4 sv = *(const uint4*)&hwp[(size_t)node * 128 + l * 16];
    float fs[16];
    unpack4_e4m3(sv.x, fs + 0);
    unpack4_e4m3(sv.y, fs + 4);
    unpack4_e4m3(sv.z, fs + 8);
    unpack4_e4m3(sv.w, fs + 12);
    float bb[16];
#pragma unroll
    for (int i = 0; i < 4; i++)
        *(float4*)&bb[4 * i] = *(const float4*)&bias[l * 16 + 4 * i];
    union { unsigned char b[16]; uint4 v; } o;
#pragma unroll
    for (int i = 0; i < 16; i++) {
        float s = fmaf(fs[i], dd, acc[i]);
        float v = fmaf(s, dd, bb[i]);
        o.b[i] = f32_to_e4m3b(fmaxf(v, 0.f));
    }
    *(uint4*)&out[(size_t)node * 128 + l * 16] = o.v;
}

// ---------------- fused head: z1->z2->z3->z4 entirely in one block ------------------

__global__ __launch_bounds__(256) void k_headall(const unsigned char* __restrict__ hb,
                                                 const int* __restrict__ orig,
                                                 const int* __restrict__ dest,
                                                 const int* __restrict__ day_ids,
                                                 const int* __restrict__ time_ids,
                                                 const int* __restrict__ mode_ids,
                                                 const float* __restrict__ CC,
                                                 const unsigned short* __restrict__ Wth1,
                                                 const unsigned short* __restrict__ Wth2,
                                                 const unsigned short* __restrict__ Wth3,
                                                 const float* __restrict__ bh2,
                                                 const float* __restrict__ bh3,
                                                 const float* __restrict__ Wh4,
                                                 const float* __restrict__ bh4,
                                                 float* __restrict__ out) {
    __shared__ __align__(16) char smem[46080];
    __shared__ int io[64], idd[64], cid[64];
    unsigned short (*Al)[72]   = (unsigned short(*)[72])smem;           // 64 x 72
    unsigned short (*Bl)[72]   = (unsigned short(*)[72])(smem + 9216);  // 256 x 72
    unsigned short (*z1s)[264] = (unsigned short(*)[264])smem;          // 64 x 264 (alias)
    unsigned short (*z2s)[136] = (unsigned short(*)[136])smem;          // 64 x 136 (alias)
    const int t = threadIdx.x;
    const int lane = t & 63, wave = t >> 6;
    const int ln = lane & 15, q8 = (lane >> 4) * 8;
    const int qr = (lane >> 4) * 4;
    const int row0 = blockIdx.x * 64;
    if (t < 64) {
        io[t] = orig[row0 + t];
        idd[t] = dest[row0 + t];
        cid[t] = (day_ids[row0 + t] * 5 + time_ids[row0 + t]) * 3 + mode_ids[row0 + t];
    }
    // ---------------- phase A: z1 = relu(gather(h) @ Wth1^T + CC) ----------------
    const int wn0 = wave * 64;
    f32x4 acc[4][4];
#pragma unroll
    for (int i = 0; i < 4; i++)
#pragma unroll
        for (int j = 0; j < 4; j++) acc[i][j] = (f32x4){0.f, 0.f, 0.f, 0.f};
    __syncthreads();

    for (int k0 = 0; k0 < 256; k0 += 64) {
        const int* idsrc = (k0 < 128) ? io : idd;
        const int kb = k0 & 64;
#pragma unroll
        for (int it = 0; it < 2; it++) {
            int c = it * 256 + t;
            int r = c >> 3, cc = (c & 7) * 8;
            uint2 u = *(const uint2*)&hb[(size_t)idsrc[r] * 128 + kb + cc];
            *(short8*)&Al[r][cc] = fp8x8_to_bf16x8(u);
        }
#pragma unroll
        for (int it = 0; it < 8; it++) {
            int c = it * 256 + t;
            int r = c >> 3, cc = (c & 7) * 8;
            *(short8*)&Bl[r][cc] = *(const short8*)&Wth1[(size_t)r * 256 + k0 + cc];
        }
        __syncthreads();
#pragma unroll
        for (int ks = 0; ks < 64; ks += 32) {
            short8 af[4], bfr[4];
#pragma unroll
            for (int i = 0; i < 4; i++)
                af[i] = *(const short8*)&Al[i * 16 + ln][ks + q8];
#pragma unroll
            for (int j = 0; j < 4; j++)
                bfr[j] = *(const short8*)&Bl[wn0 + j * 16 + ln][ks + q8];
#pragma unroll
            for (int i = 0; i < 4; i++)
#pragma unroll
                for (int j = 0; j < 4; j++)
                    acc[i][j] = __builtin_amdgcn_mfma_f32_16x16x32_bf16(af[i], bfr[j], acc[i][j], 0, 0, 0);
        }
        __syncthreads();   // all waves done with Al/Bl -> safe to alias as z1s
    }
    // epilogue A -> z1s (bf16, in LDS)
#pragma unroll
    for (int i = 0; i < 4; i++) {
#pragma unroll
        for (int j = 0; j < 4; j++) {
            int col = wn0 + j * 16 + ln;
#pragma unroll
            for (int r = 0; r < 4; r++) {
                int rl = i * 16 + qr + r;
                float v = acc[i][j][r] + CC[cid[rl] * 256 + col];
                z1s[rl][col] = bf16_rn(fmaxf(v, 0.f));
            }
        }
    }
    __syncthreads();
    // ---------------- phase B: z2 = relu(z1 @ Wth2^T + bh2) ----------------
    const int bcol0 = wave * 32;
    f32x4 acc2[4][2];
#pragma unroll
    for (int i = 0; i < 4; i++)
#pragma unroll
        for (int j = 0; j < 2; j++) acc2[i][j] = (f32x4){0.f, 0.f, 0.f, 0.f};
#pragma unroll
    for (int ks = 0; ks < 256; ks += 32) {
        short8 af[4], bfr[2];
#pragma unroll
        for (int i = 0; i < 4; i++)
            af[i] = *(const short8*)&z1s[i * 16 + ln][ks + q8];
#pragma unroll
        for (int j = 0; j < 2; j++)
            bfr[j] = *(const short8*)&Wth2[(size_t)(bcol0 + j * 16 + ln) * 256 + ks + q8];
#pragma unroll
        for (int i = 0; i < 4; i++)
#pragma unroll
            for (int j = 0; j < 2; j++)
                acc2[i][j] = __builtin_amdgcn_mfma_f32_16x16x32_bf16(af[i], bfr[j], acc2[i][j], 0, 0, 0);
    }
    __syncthreads();   // all waves done reading z1s -> safe to alias as z2s
#pragma unroll
    for (int i = 0; i < 4; i++) {
#pragma unroll
        for (int j = 0; j < 2; j++) {
            int col = bcol0 + j * 16 + ln;
            float bv = bh2[col];
#pragma unroll
            for (int r = 0; r < 4; r++) {
                int row = i * 16 + qr + r;
                z2s[row][col] = bf16_rn(fmaxf(acc2[i][j][r] + bv, 0.f));
            }
        }
    }
    __syncthreads();
    // ---------------- phase C: out = sigmoid(relu(z2 @ Wth3^T + bh3) . Wh4 + bh4) ----
    const int wr0 = wave * 16;
    f32x4 acc3[4];
#pragma unroll
    for (int j = 0; j < 4; j++) acc3[j] = (f32x4){0.f, 0.f, 0.f, 0.f};
#pragma unroll
    for (int ks = 0; ks < 128; ks += 32) {
        short8 af = *(const short8*)&z2s[wr0 + ln][ks + q8];
#pragma unroll
        for (int j = 0; j < 4; j++) {
            short8 bfr = *(const short8*)&Wth3[(size_t)(j * 16 + ln) * 128 + ks + q8];
            acc3[j] = __builtin_amdgcn_mfma_f32_16x16x32_bf16(af, bfr, acc3[j], 0, 0, 0);
        }
    }
    float b3c[4], w4c[4];
#pragma unroll
    for (int j = 0; j < 4; j++) {
        b3c[j] = bh3[j * 16 + ln];
        w4c[j] = Wh4[j * 16 + ln];
    }
    float b4 = bh4[0];
    float part[4];
#pragma unroll
    for (int r = 0; r < 4; r++) {
        float s = 0.f;
#pragma unroll
        for (int j = 0; j < 4; j++)
            s = fmaf(fmaxf(acc3[j][r] + b3c[j], 0.f), w4c[j], s);
        part[r] = s;
    }
#pragma unroll
    for (int r = 0; r < 4; r++) {
        float s = part[r];
        s += __shfl_xor(s, 1); s += __shfl_xor(s, 2);
        s += __shfl_xor(s, 4); s += __shfl_xor(s, 8);
        part[r] = s;
    }
    if (ln == 0) {
#pragma unroll
        for (int r = 0; r < 4; r++)
            out[row0 + wr0 + qr + r] = 1.0f / (1.0f + expf(-(part[r] + b4)));
    }
}

// ---------------- launch ------------------------------------------------------------

extern "C" void kernel_launch(void* const* d_in, const int* in_sizes, int n_in,
                              void* d_out, int out_size, void* d_ws, size_t ws_size,
                              hipStream_t stream) {
    const float* x          = (const float*)d_in[0];
    const int*   eidx       = (const int*)d_in[1];
    const int*   esrc       = eidx;
    const int*   edst       = eidx + EE;
    const int*   origin     = (const int*)d_in[2];
    const int*   destid     = (const int*)d_in[3];
    const int*   day_ids    = (const int*)d_in[4];
    const int*   time_ids   = (const int*)d_in[5];
    const int*   mode_ids   = (const int*)d_in[6];
    const float* W1 = (const float*)d_in[7];   const float* b1 = (const float*)d_in[8];
    const float* W2 = (const float*)d_in[9];   const float* b2 = (const float*)d_in[10];
    const float* W3 = (const float*)d_in[11];  const float* b3 = (const float*)d_in[12];
    const float* day_table  = (const float*)d_in[13];
    const float* time_table = (const float*)d_in[14];
    const float* mode_table = (const float*)d_in[15];
    const float* Wf  = (const float*)d_in[16]; const float* bf  = (const float*)d_in[17];
    const float* Wh1 = (const float*)d_in[18]; const float* bh1 = (const float*)d_in[19];
    const float* Wh2 = (const float*)d_in[20]; const float* bh2 = (const float*)d_in[21];
    const float* Wh3 = (const float*)d_in[22]; const float* bh3 = (const float*)d_in[23];
    const float* Wh4 = (const float*)d_in[24]; const float* bh4 = (const float*)d_in[25];
    float* out = (float*)d_out;

    char* wsb = (char*)d_ws;
    size_t off = 0;
    auto alloc = [&](size_t bytes) -> char* {
        char* p = wsb + off;
        off = (off + bytes + 511) & ~(size_t)511;
        return p;
    };
    // zero-initialized block: bcnt | bcur0 (one memset)
    int*   zblk    = (int*)alloc((2 * NBK + 1) * 4);
    int*   bcnt    = zblk;
    int*   bcur0   = zblk + (NBK + 1);
    int*   offsets = (int*)alloc((size_t)(NN + 1) * 4);
    float* dinv    = (float*)alloc((size_t)NN * 4);
    int2*  binned  = (int2*)alloc((size_t)EE * 8);
    int*   epsrc   = (int*)alloc((size_t)EE * 4);
    unsigned short* Wt1  = (unsigned short*)alloc(128 * 128 * 2);
    unsigned short* Wt2  = (unsigned short*)alloc(128 * 128 * 2);
    unsigned short* Wt3  = (unsigned short*)alloc(128 * 128 * 2);
    unsigned short* Wtf  = (unsigned short*)alloc(128 * 128 * 2);
    unsigned short* Wth1 = (unsigned short*)alloc(256 * 256 * 2);
    unsigned short* Wth2 = (unsigned short*)alloc(128 * 256 * 2);
    unsigned short* Wth3 = (unsigned short*)alloc(64 * 128 * 2);
    float* CC = (float*)alloc(30 * 256 * 4);
    unsigned char*  bufHW = (unsigned char*)alloc((size_t)NN * 128);   // fp8 hw
    unsigned char*  bufH  = (unsigned char*)alloc((size_t)NN * 128);   // fp8 h

    hipMemsetAsync(zblk, 0, (2 * NBK + 1) * 4, stream);
    k_bcount<<<BINB, 1024, 0, stream>>>(edst, bcnt);
    k_bin<<<BINB, 1024, 0, stream>>>(esrc, edst, bcnt, bcur0, binned);
    k_boffplace<<<NBK, 256, 0, stream>>>(binned, bcnt, offsets, dinv, epsrc);

    k_wtcc<<<672 + 30, 256, 0, stream>>>(W1, W2, W3, Wf, Wh1, Wh2, Wh3,
                                         Wt1, Wt2, Wt3, Wtf, Wth1, Wth2, Wth3,
                                         day_table, time_table, mode_table, bf, bh1, CC);

    const int GB = (NN + 127) / 128;   // 782
    const int AB = (NN + 31) / 32;     // 3125 blocks, 32 nodes/block
    k_mfma<128, 128, 4, 0, 2, 1><<<dim3(GB, 1), 256, 0, stream>>>(x, Wt1, nullptr, bufHW, NN, 128);
    k_agg8<<<AB, 256, 0, stream>>>(bufHW, epsrc, offsets, dinv, b1, bufH);
    k_mfma<128, 128, 4, 0, 2, 2><<<dim3(GB, 1), 256, 0, stream>>>(bufH, Wt2, nullptr, bufHW, NN, 128);
    k_agg8<<<AB, 256, 0, stream>>>(bufHW, epsrc, offsets, dinv, b2, bufH);
    k_mfma<128, 128, 4, 0, 2, 2><<<dim3(GB, 1), 256, 0, stream>>>(bufH, Wt3, nullptr, bufHW, NN, 128);
    k_agg8<<<AB, 256, 0, stream>>>(bufHW, epsrc, offsets, dinv, b3, bufH);
    // final h = bufH (fp8)

    k_headall<<<BQ / 64, 256, 0, stream>>>(bufH, origin, destid, day_ids, time_ids,
                                           mode_ids, CC, Wth1, Wth2, Wth3,
                                           bh2, bh3, Wh4, bh4, out);
}

// Round 5
// 400.009 us; speedup vs baseline: 1.8140x; 1.0791x over previous
//
#include <hip/hip_runtime.h>

#define NN 100000   // nodes
#define EE 1600000  // edges
#define BQ 65536    // queries
#define NBK 391     // node buckets of 256 (ceil(NN/256))
#define BINB 256    // binning grid: 256 blocks keeps >=128B runs per (block,bucket)
#define ECH 6250    // edges per binning block (EE/BINB)

typedef __attribute__((ext_vector_type(8))) short short8;
typedef __attribute__((ext_vector_type(4))) float f32x4;
typedef __attribute__((ext_vector_type(2))) float f32x2;

__device__ __forceinline__ unsigned short bf16_rn(float f) {
    unsigned u = __builtin_bit_cast(unsigned, f);
    u += 0x7fff + ((u >> 16) & 1);
    return (unsigned short)(u >> 16);
}

// ---------------- fp8 e4m3 helpers (HW cvt with SW fallback) ------------------------

#if defined(__has_builtin)
#if __has_builtin(__builtin_amdgcn_cvt_pk_fp8_f32) && __has_builtin(__builtin_amdgcn_cvt_pk_f32_fp8)
#define HW_FP8 1
#endif
#endif
#ifndef HW_FP8
#define HW_FP8 0
#endif

__device__ __forceinline__ unsigned char sw_f32_to_e4m3(float f) {
    float a = fabsf(f);
    unsigned s = __builtin_bit_cast(unsigned, f) >> 31;
    if (!(a < 448.f)) return (unsigned char)((s << 7) | 0x7E);
    if (a < 0.015625f) {
        int q = (int)rintf(a * 512.0f);
        return (unsigned char)((s << 7) | q);
    }
    int e; float m = frexpf(a, &e);
    int q = (int)rintf(m * 16.0f);
    int exp = e - 1 + 7;
    if (q == 16) { q = 8; exp++; }
    if (exp >= 16 || (exp == 15 && q == 15)) return (unsigned char)((s << 7) | 0x7E);
    return (unsigned char)((s << 7) | (exp << 3) | (q - 8));
}
__device__ __forceinline__ float sw_e4m3_to_f32(unsigned char v) {
    unsigned s = v >> 7, e = (v >> 3) & 15, m = v & 7;
    float r = e ? ldexpf((float)(8 + m), (int)e - 10) : ldexpf((float)m, -9);
    return s ? -r : r;
}

__device__ __forceinline__ unsigned char f32_to_e4m3b(float f) {
#if HW_FP8
    return (unsigned char)(__builtin_amdgcn_cvt_pk_fp8_f32(f, f, 0, false) & 0xFF);
#else
    return sw_f32_to_e4m3(f);
#endif
}
__device__ __forceinline__ void unpack4_e4m3(unsigned v, float* o) {
#if HW_FP8
    f32x2 lo = __builtin_amdgcn_cvt_pk_f32_fp8((int)v, false);
    f32x2 hi = __builtin_amdgcn_cvt_pk_f32_fp8((int)v, true);
    o[0] = lo[0]; o[1] = lo[1]; o[2] = hi[0]; o[3] = hi[1];
#else
    o[0] = sw_e4m3_to_f32(v & 0xFF);
    o[1] = sw_e4m3_to_f32((v >> 8) & 0xFF);
    o[2] = sw_e4m3_to_f32((v >> 16) & 0xFF);
    o[3] = sw_e4m3_to_f32((v >> 24) & 0xFF);
#endif
}
// 8 fp8 -> 8 bf16 (exact)
__device__ __forceinline__ short8 fp8x8_to_bf16x8(uint2 u) {
    float f[8];
    unpack4_e4m3(u.x, f);
    unpack4_e4m3(u.y, f + 4);
    union { unsigned short s[8]; short8 v; } o;
#pragma unroll
    for (int i = 0; i < 8; i++) o.s[i] = bf16_rn(f[i]);
    return o.v;
}

// ---------------- bucket count / bin / offsets+place --------------------------------

__global__ __launch_bounds__(1024) void k_bcount(const int* __restrict__ dst,
                                                 int* __restrict__ bcnt) {
    __shared__ int h[NBK];
    int t = threadIdx.x, b = blockIdx.x;
    for (int j = t; j < NBK; j += 1024) h[j] = 0;
    __syncthreads();
    int lo = b * ECH, hi = lo + ECH;
    for (int i = lo + t; i < hi; i += 1024) atomicAdd(&h[dst[i] >> 8], 1);
    __syncthreads();
    for (int j = t; j < NBK; j += 1024)
        if (h[j]) atomicAdd(&bcnt[j], h[j]);
}

__global__ __launch_bounds__(1024) void k_bin(const int* __restrict__ src,
                                              const int* __restrict__ dst,
                                              const int* __restrict__ bcnt,
                                              int* __restrict__ bcur0,
                                              int2* __restrict__ binned) {
    __shared__ int h[NBK];
    __shared__ int cur[NBK];
    __shared__ int sd[512];
    int t = threadIdx.x, b = blockIdx.x;
    for (int j = t; j < NBK; j += 1024) { h[j] = 0; cur[j] = 0; }
    if (t < 512) sd[t] = (t < NBK) ? bcnt[t] : 0;
    __syncthreads();
    int lo = b * ECH, hi = lo + ECH;
    for (int i = lo + t; i < hi; i += 1024) atomicAdd(&h[dst[i] >> 8], 1);
    for (int o = 1; o < 512; o <<= 1) {
        int x = 0;
        if (t < 512 && t >= o) x = sd[t - o];
        __syncthreads();
        if (t < 512) sd[t] += x;
        __syncthreads();
    }
    for (int j = t; j < NBK; j += 1024)
        if (h[j]) h[j] = (sd[j] - bcnt[j]) + atomicAdd(&bcur0[j], h[j]);
    __syncthreads();
    for (int i = lo + t; i < hi; i += 1024) {
        int d = dst[i], bk = d >> 8;
        int pos = h[bk] + atomicAdd(&cur[bk], 1);
        binned[pos] = make_int2(src[i], d);
    }
}

__global__ __launch_bounds__(256) void k_boffplace(const int2* __restrict__ binned,
                                                   const int* __restrict__ bcnt,
                                                   int* __restrict__ offsets,
                                                   float* __restrict__ dinv,
                                                   int* __restrict__ epsrc) {
    __shared__ int lh[256];
    __shared__ int sd[256];
    int t = threadIdx.x, b = blockIdx.x;
    lh[t] = 0;
    int part = 0;
    for (int j = t; j < b; j += 256) part += bcnt[j];
    sd[t] = part;
    __syncthreads();
    for (int o = 128; o > 0; o >>= 1) {
        if (t < o) sd[t] += sd[t + o];
        __syncthreads();
    }
    const int lo = sd[0];
    const int hi = lo + bcnt[b];
    __syncthreads();
    for (int i = lo + t; i < hi; i += 256) atomicAdd(&lh[binned[i].y & 255], 1);
    __syncthreads();
    int v = lh[t];
    sd[t] = v;
    __syncthreads();
    for (int o = 1; o < 256; o <<= 1) {
        int x = (t >= o) ? sd[t - o] : 0;
        __syncthreads();
        sd[t] += x;
        __syncthreads();
    }
    int node = (b << 8) + t;
    int myoff = lo + sd[t] - v;
    if (node < NN) {
        offsets[node] = myoff;
        dinv[node] = rsqrtf((float)v + 1.0f);
    }
    if (b == NBK - 1 && t == 0) offsets[NN] = EE;
    __syncthreads();
    lh[t] = myoff;
    __syncthreads();
    for (int i = lo + t; i < hi; i += 256) {
        int2 e = binned[i];
        int pos = atomicAdd(&lh[e.y & 255], 1);
        epsrc[pos] = e.x;
    }
}

// ---------------- fused weight convert + CC table (independent, one launch) ---------

__global__ __launch_bounds__(256) void k_wtcc(const float* __restrict__ W1,
                                              const float* __restrict__ W2,
                                              const float* __restrict__ W3,
                                              const float* __restrict__ Wf,
                                              const float* __restrict__ Wh1,
                                              const float* __restrict__ Wh2,
                                              const float* __restrict__ Wh3,
                                              unsigned short* __restrict__ Wt1,
                                              unsigned short* __restrict__ Wt2,
                                              unsigned short* __restrict__ Wt3,
                                              unsigned short* __restrict__ Wtf,
                                              unsigned short* __restrict__ Wth1,
                                              unsigned short* __restrict__ Wth2,
                                              unsigned short* __restrict__ Wth3,
                                              const float* __restrict__ day_table,
                                              const float* __restrict__ time_table,
                                              const float* __restrict__ mode_table,
                                              const float* __restrict__ bf,
                                              const float* __restrict__ bh1,
                                              float* __restrict__ CC) {
    if (blockIdx.x < 672) {
        int i = blockIdx.x * 256 + threadIdx.x;
        const float* W; unsigned short* Wt; int K, N, idx;
        if (i < 16384)       { W = W1;  Wt = Wt1;  K = 128; N = 128; idx = i; }
        else if (i < 32768)  { W = W2;  Wt = Wt2;  K = 128; N = 128; idx = i - 16384; }
        else if (i < 49152)  { W = W3;  Wt = Wt3;  K = 128; N = 128; idx = i - 32768; }
        else if (i < 65536)  { W = Wf;  Wt = Wtf;  K = 128; N = 128; idx = i - 49152; }
        else if (i < 131072) { W = Wh1; Wt = Wth1; K = 256; N = 256; idx = i - 65536; }
        else if (i < 163840) { W = Wh2; Wt = Wth2; K = 256; N = 128; idx = i - 131072; }
        else if (i < 172032) { W = Wh3; Wt = Wth3; K = 128; N = 64;  idx = i - 163840; }
        else return;
        int k = idx / N, n = idx % N;
        Wt[(size_t)n * K + k] = bf16_rn(W[idx]);
    } else {
        int c = blockIdx.x - 672;             // 0..29
        int mode = c % 3, dt = c / 3, time = dt % 5, day = dt / 5;
        __shared__ float temp[128];
        int t = threadIdx.x;
        if (t < 128) {
            float s = bf[t];
            for (int j = 0; j < 64; j++) s = fmaf(day_table[day * 64 + j],  Wf[j * 128 + t], s);
            for (int j = 0; j < 64; j++) s = fmaf(time_table[time * 64 + j], Wf[(64 + j) * 128 + t], s);
            temp[t] = fmaxf(s, 0.f);
        }
        __syncthreads();
        float s = bh1[t];
        for (int k = 0; k < 128; k++) s = fmaf(temp[k], Wh1[(size_t)(256 + k) * 256 + t], s);
        for (int j = 0; j < 64; j++)  s = fmaf(mode_table[mode * 64 + j], Wh1[(size_t)(384 + j) * 256 + t], s);
        CC[c * 256 + t] = s;
    }
}

// ---------------- bf16 MFMA GEMM: C = A @ Wt^T (+bias)(+relu) -----------------------
// OUTM: 0=f32, 1=bf16, 2=fp8-e4m3. AMODE: 0=bf16, 1=f32, 2=fp8.

template <int K, int BN, int TN, int ACT, int OUTM, int AMODE>
__global__ __launch_bounds__(256) void k_mfma(const void* __restrict__ Ap,
                                              const unsigned short* __restrict__ Wt,
                                              const float* __restrict__ bias,
                                              void* __restrict__ Cp,
                                              int M, int Ntot) {
    constexpr int TM = 4;
    __shared__ unsigned short Al[128][72];
    __shared__ unsigned short Bl[BN][72];
    const int t = threadIdx.x;
    const int lane = t & 63, wave = t >> 6;
    const int ln = lane & 15, q8 = (lane >> 4) * 8;
    const int row0 = blockIdx.x * 128;
    const int col0 = blockIdx.y * BN;
    const int wm0 = (wave >> 1) * 64;
    const int wn0 = (wave & 1) * (TN * 16);
    f32x4 acc[TM][TN];
#pragma unroll
    for (int i = 0; i < TM; i++)
#pragma unroll
        for (int j = 0; j < TN; j++) acc[i][j] = (f32x4){0.f, 0.f, 0.f, 0.f};

    for (int k0 = 0; k0 < K; k0 += 64) {
#pragma unroll
        for (int it = 0; it < 4; it++) {
            int c = it * 256 + t;
            int r = c >> 3, cc = (c & 7) * 8;
            int grow = row0 + r;
            if (AMODE == 1) {
                const float* A = (const float*)Ap;
                union { unsigned short u[8]; short8 v; } tm8;
                if (grow < M) {
                    float4 v0 = *(const float4*)&A[(size_t)grow * K + k0 + cc];
                    float4 v1 = *(const float4*)&A[(size_t)grow * K + k0 + cc + 4];
                    tm8.u[0] = bf16_rn(v0.x); tm8.u[1] = bf16_rn(v0.y);
                    tm8.u[2] = bf16_rn(v0.z); tm8.u[3] = bf16_rn(v0.w);
                    tm8.u[4] = bf16_rn(v1.x); tm8.u[5] = bf16_rn(v1.y);
                    tm8.u[6] = bf16_rn(v1.z); tm8.u[7] = bf16_rn(v1.w);
                } else {
                    tm8.v = (short8){0, 0, 0, 0, 0, 0, 0, 0};
                }
                *(short8*)&Al[r][cc] = tm8.v;
            } else if (AMODE == 2) {
                const unsigned char* A = (const unsigned char*)Ap;
                short8 v = (short8){0, 0, 0, 0, 0, 0, 0, 0};
                if (grow < M) {
                    uint2 u = *(const uint2*)&A[(size_t)grow * K + k0 + cc];
                    v = fp8x8_to_bf16x8(u);
                }
                *(short8*)&Al[r][cc] = v;
            } else {
                const unsigned short* A = (const unsigned short*)Ap;
                short8 v = (short8){0, 0, 0, 0, 0, 0, 0, 0};
                if (grow < M) v = *(const short8*)&A[(size_t)grow * K + k0 + cc];
                *(short8*)&Al[r][cc] = v;
            }
        }
#pragma unroll
        for (int it = 0; it < BN / 32; it++) {
            int c = it * 256 + t;
            int r = c >> 3, cc = (c & 7) * 8;
            *(short8*)&Bl[r][cc] = *(const short8*)&Wt[(size_t)(col0 + r) * K + k0 + cc];
        }
        __syncthreads();
#pragma unroll
        for (int ks = 0; ks < 64; ks += 32) {
            short8 af[TM], bfr[TN];
#pragma unroll
            for (int i = 0; i < TM; i++)
                af[i] = *(const short8*)&Al[wm0 + i * 16 + ln][ks + q8];
#pragma unroll
            for (int j = 0; j < TN; j++)
                bfr[j] = *(const short8*)&Bl[wn0 + j * 16 + ln][ks + q8];
#pragma unroll
            for (int i = 0; i < TM; i++)
#pragma unroll
                for (int j = 0; j < TN; j++)
                    acc[i][j] = __builtin_amdgcn_mfma_f32_16x16x32_bf16(af[i], bfr[j], acc[i][j], 0, 0, 0);
        }
        __syncthreads();
    }
    const int qr = (lane >> 4) * 4;
#pragma unroll
    for (int i = 0; i < TM; i++) {
#pragma unroll
        for (int j = 0; j < TN; j++) {
            int col = col0 + wn0 + j * 16 + ln;
            float bv = bias ? bias[col] : 0.f;
#pragma unroll
            for (int r = 0; r < 4; r++) {
                int row = row0 + wm0 + i * 16 + qr + r;
                if (row < M) {
                    float v = acc[i][j][r] + bv;
                    if (ACT) v = fmaxf(v, 0.f);
                    if (OUTM == 1)      ((unsigned short*)Cp)[(size_t)row * Ntot + col] = bf16_rn(v);
                    else if (OUTM == 2) ((unsigned char*)Cp)[(size_t)row * Ntot + col] = f32_to_e4m3b(v);
                    else                ((float*)Cp)[(size_t)row * Ntot + col] = v;
                }
            }
        }
    }
}

// ---------------- pipelined fp8 row-gather accumulate -------------------------------
// 2-deep software pipeline: batch k+1's epsrc/dinv/row loads issue before batch k's
// unpack+fma, doubling rows-in-flight (latency-bound L3 gather, R4 analysis).

__device__ __forceinline__ void gather_rows(const unsigned char* __restrict__ hwp,
                                            const int* __restrict__ epsrc,
                                            const float* __restrict__ dinv,
                                            int beg, int end, int l,
                                            float acc[16]) {
    int pA[8], pB[8];
    float cA[8], cB[8];
    uint4 vA[8], vB[8];
    int e = beg;
    if (e >= end) return;
#pragma unroll
    for (int j = 0; j < 8; j++) { int ee = e + j; pA[j] = epsrc[ee < end ? ee : end - 1]; }
#pragma unroll
    for (int j = 0; j < 8; j++) cA[j] = dinv[pA[j]];
#pragma unroll
    for (int j = 0; j < 8; j++) vA[j] = *(const uint4*)&hwp[(size_t)pA[j] * 128 + l * 16];
    for (; e + 8 < end; e += 16) {
#pragma unroll
        for (int j = 0; j < 8; j++) { int ee = e + 8 + j; pB[j] = epsrc[ee < end ? ee : end - 1]; }
#pragma unroll
        for (int j = 0; j < 8; j++) cB[j] = dinv[pB[j]];
#pragma unroll
        for (int j = 0; j < 8; j++) vB[j] = *(const uint4*)&hwp[(size_t)pB[j] * 128 + l * 16];
#pragma unroll
        for (int j = 0; j < 8; j++) {
            float c = (e + j < end) ? cA[j] : 0.f;
            float f[16];
            unpack4_e4m3(vA[j].x, f + 0);
            unpack4_e4m3(vA[j].y, f + 4);
            unpack4_e4m3(vA[j].z, f + 8);
            unpack4_e4m3(vA[j].w, f + 12);
#pragma unroll
            for (int i = 0; i < 16; i++) acc[i] = fmaf(f[i], c, acc[i]);
        }
        if (e + 16 < end) {
#pragma unroll
            for (int j = 0; j < 8; j++) { int ee = e + 16 + j; pA[j] = epsrc[ee < end ? ee : end - 1]; }
#pragma unroll
            for (int j = 0; j < 8; j++) cA[j] = dinv[pA[j]];
#pragma unroll
            for (int j = 0; j < 8; j++) vA[j] = *(const uint4*)&hwp[(size_t)pA[j] * 128 + l * 16];
        }
#pragma unroll
        for (int j = 0; j < 8; j++) {
            float c = (e + 8 + j < end) ? cB[j] : 0.f;
            float f[16];
            unpack4_e4m3(vB[j].x, f + 0);
            unpack4_e4m3(vB[j].y, f + 4);
            unpack4_e4m3(vB[j].z, f + 8);
            unpack4_e4m3(vB[j].w, f + 12);
#pragma unroll
            for (int i = 0; i < 16; i++) acc[i] = fmaf(f[i], c, acc[i]);
        }
    }
    if (e < end) {
#pragma unroll
        for (int j = 0; j < 8; j++) {
            float c = (e + j < end) ? cA[j] : 0.f;
            float f[16];
            unpack4_e4m3(vA[j].x, f + 0);
            unpack4_e4m3(vA[j].y, f + 4);
            unpack4_e4m3(vA[j].z, f + 8);
            unpack4_e4m3(vA[j].w, f + 12);
#pragma unroll
            for (int i = 0; i < 16; i++) acc[i] = fmaf(f[i], c, acc[i]);
        }
    }
}

// ---------------- layer-1 edge aggregation (fp8 gather of hw) -----------------------
// out = fp8(relu(D(A+I)D hw + b)), wave = 8 nodes x 8 lanes.

__global__ __launch_bounds__(256) void k_agg8(const unsigned char* __restrict__ hwp,
                                              const int* __restrict__ epsrc,
                                              const int* __restrict__ offsets,
                                              const float* __restrict__ dinv,
                                              const float* __restrict__ bias,
                                              unsigned char* __restrict__ out) {
    const int wid = blockIdx.x * 4 + (threadIdx.x >> 6);
    const int lane = threadIdx.x & 63;
    const int g = lane >> 3, l = lane & 7;
    const int node = wid * 8 + g;
    if (node >= NN) return;
    float acc[16];
#pragma unroll
    for (int i = 0; i < 16; i++) acc[i] = 0.f;
    gather_rows(hwp, epsrc, dinv, offsets[node], offsets[node + 1], l, acc);
    float dd = dinv[node];
    uint4 sv = *(const uint4*)&hwp[(size_t)node * 128 + l * 16];
    float fs[16];
    unpack4_e4m3(sv.x, fs + 0);
    unpack4_e4m3(sv.y, fs + 4);
    unpack4_e4m3(sv.z, fs + 8);
    unpack4_e4m3(sv.w, fs + 12);
    float bb[16];
#pragma unroll
    for (int i = 0; i < 4; i++)
        *(float4*)&bb[4 * i] = *(const float4*)&bias[l * 16 + 4 * i];
    union { unsigned char b[16]; uint4 v; } o;
#pragma unroll
    for (int i = 0; i < 16; i++) {
        float s = fmaf(fs[i], dd, acc[i]);
        float v = fmaf(s, dd, bb[i]);
        o.b[i] = f32_to_e4m3b(fmaxf(v, 0.f));
    }
    *(uint4*)&out[(size_t)node * 128 + l * 16] = o.v;
}

// ---------------- fused agg+GEMM for layers 2/3: out = fp8(relu((D(A+I)D h)@W + b)) --
// GCN associativity: (A h) W == A (h W). Gathers fp8 h (one quantization per layer
// instead of two), stages the 32x128 agg tile in LDS (stride 130: A-frag reads are
// 2-way/free), MFMA vs L2-resident Wt, bias+relu+fp8 epilogue. NN%32==0: no tails.

__global__ __launch_bounds__(256) void k_aggmm(const unsigned char* __restrict__ hp,
                                               const int* __restrict__ epsrc,
                                               const int* __restrict__ offsets,
                                               const float* __restrict__ dinv,
                                               const unsigned short* __restrict__ Wt,
                                               const float* __restrict__ bias,
                                               unsigned char* __restrict__ out) {
    __shared__ unsigned short As[32][130];
    const int t = threadIdx.x;
    const int lane = t & 63, wave = t >> 6;
    const int g = lane >> 3, l = lane & 7;
    const int node0 = blockIdx.x * 32;
    const int arow = wave * 8 + g;            // 0..31
    const int node = node0 + arow;
    // ---- gather phase ----
    float acc[16];
#pragma unroll
    for (int i = 0; i < 16; i++) acc[i] = 0.f;
    gather_rows(hp, epsrc, dinv, offsets[node], offsets[node + 1], l, acc);
    float dd = dinv[node];
    uint4 sv = *(const uint4*)&hp[(size_t)node * 128 + l * 16];
    float fs[16];
    unpack4_e4m3(sv.x, fs + 0);
    unpack4_e4m3(sv.y, fs + 4);
    unpack4_e4m3(sv.z, fs + 8);
    unpack4_e4m3(sv.w, fs + 12);
    union { unsigned short u[16]; short8 v[2]; } ab;
#pragma unroll
    for (int i = 0; i < 16; i++)
        ab.u[i] = bf16_rn(fmaf(fs[i], dd, acc[i]) * dd);
    *(short8*)&As[arow][l * 16] = ab.v[0];
    *(short8*)&As[arow][l * 16 + 8] = ab.v[1];
    __syncthreads();
    // ---- MFMA phase: C[32x128] = As @ Wt^T ----
    const int ln = lane & 15, q8 = (lane >> 4) * 8;
    const int colb = wave * 32;
    f32x4 am[2][2];
#pragma unroll
    for (int i = 0; i < 2; i++)
#pragma unroll
        for (int j = 0; j < 2; j++) am[i][j] = (f32x4){0.f, 0.f, 0.f, 0.f};
#pragma unroll
    for (int ks = 0; ks < 128; ks += 32) {
        short8 af[2], bfr[2];
#pragma unroll
        for (int i = 0; i < 2; i++)
            af[i] = *(const short8*)&As[i * 16 + ln][ks + q8];
#pragma unroll
        for (int j = 0; j < 2; j++)
            bfr[j] = *(const short8*)&Wt[(size_t)(colb + j * 16 + ln) * 128 + ks + q8];
#pragma unroll
        for (int i = 0; i < 2; i++)
#pragma unroll
            for (int j = 0; j < 2; j++)
                am[i][j] = __builtin_amdgcn_mfma_f32_16x16x32_bf16(af[i], bfr[j], am[i][j], 0, 0, 0);
    }
    const int qr = (lane >> 4) * 4;
#pragma unroll
    for (int i = 0; i < 2; i++) {
#pragma unroll
        for (int j = 0; j < 2; j++) {
            int col = colb + j * 16 + ln;
            float bv = bias[col];
#pragma unroll
            for (int r = 0; r < 4; r++) {
                int row = i * 16 + qr + r;
                out[(size_t)(node0 + row) * 128 + col] =
                    f32_to_e4m3b(fmaxf(am[i][j][r] + bv, 0.f));
            }
        }
    }
}

// ---------------- fused head: z1->z2->z3->z4 entirely in one block ------------------

__global__ __launch_bounds__(256) void k_headall(const unsigned char* __restrict__ hb,
                                                 const int* __restrict__ orig,
                                                 const int* __restrict__ dest,
                                                 const int* __restrict__ day_ids,
                                                 const int* __restrict__ time_ids,
                                                 const int* __restrict__ mode_ids,
                                                 const float* __restrict__ CC,
                                                 const unsigned short* __restrict__ Wth1,
                                                 const unsigned short* __restrict__ Wth2,
                                                 const unsigned short* __restrict__ Wth3,
                                                 const float* __restrict__ bh2,
                                                 const float* __restrict__ bh3,
                                                 const float* __restrict__ Wh4,
                                                 const float* __restrict__ bh4,
                                                 float* __restrict__ out) {
    __shared__ __align__(16) char smem[46080];
    __shared__ int io[64], idd[64], cid[64];
    unsigned short (*Al)[72]   = (unsigned short(*)[72])smem;           // 64 x 72
    unsigned short (*Bl)[72]   = (unsigned short(*)[72])(smem + 9216);  // 256 x 72
    unsigned short (*z1s)[264] = (unsigned short(*)[264])smem;          // 64 x 264 (alias)
    unsigned short (*z2s)[136] = (unsigned short(*)[136])smem;          // 64 x 136 (alias)
    const int t = threadIdx.x;
    const int lane = t & 63, wave = t >> 6;
    const int ln = lane & 15, q8 = (lane >> 4) * 8;
    const int qr = (lane >> 4) * 4;
    const int row0 = blockIdx.x * 64;
    if (t < 64) {
        io[t] = orig[row0 + t];
        idd[t] = dest[row0 + t];
        cid[t] = (day_ids[row0 + t] * 5 + time_ids[row0 + t]) * 3 + mode_ids[row0 + t];
    }
    // ---------------- phase A: z1 = relu(gather(h) @ Wth1^T + CC) ----------------
    const int wn0 = wave * 64;
    f32x4 acc[4][4];
#pragma unroll
    for (int i = 0; i < 4; i++)
#pragma unroll
        for (int j = 0; j < 4; j++) acc[i][j] = (f32x4){0.f, 0.f, 0.f, 0.f};
    __syncthreads();

    for (int k0 = 0; k0 < 256; k0 += 64) {
        const int* idsrc = (k0 < 128) ? io : idd;
        const int kb = k0 & 64;
#pragma unroll
        for (int it = 0; it < 2; it++) {
            int c = it * 256 + t;
            int r = c >> 3, cc = (c & 7) * 8;
            uint2 u = *(const uint2*)&hb[(size_t)idsrc[r] * 128 + kb + cc];
            *(short8*)&Al[r][cc] = fp8x8_to_bf16x8(u);
        }
#pragma unroll
        for (int it = 0; it < 8; it++) {
            int c = it * 256 + t;
            int r = c >> 3, cc = (c & 7) * 8;
            *(short8*)&Bl[r][cc] = *(const short8*)&Wth1[(size_t)r * 256 + k0 + cc];
        }
        __syncthreads();
#pragma unroll
        for (int ks = 0; ks < 64; ks += 32) {
            short8 af[4], bfr[4];
#pragma unroll
            for (int i = 0; i < 4; i++)
                af[i] = *(const short8*)&Al[i * 16 + ln][ks + q8];
#pragma unroll
            for (int j = 0; j < 4; j++)
                bfr[j] = *(const short8*)&Bl[wn0 + j * 16 + ln][ks + q8];
#pragma unroll
            for (int i = 0; i < 4; i++)
#pragma unroll
                for (int j = 0; j < 4; j++)
                    acc[i][j] = __builtin_amdgcn_mfma_f32_16x16x32_bf16(af[i], bfr[j], acc[i][j], 0, 0, 0);
        }
        __syncthreads();   // all waves done with Al/Bl -> safe to alias as z1s
    }
    // epilogue A -> z1s (bf16, in LDS)
#pragma unroll
    for (int i = 0; i < 4; i++) {
#pragma unroll
        for (int j = 0; j < 4; j++) {
            int col = wn0 + j * 16 + ln;
#pragma unroll
            for (int r = 0; r < 4; r++) {
                int rl = i * 16 + qr + r;
                float v = acc[i][j][r] + CC[cid[rl] * 256 + col];
                z1s[rl][col] = bf16_rn(fmaxf(v, 0.f));
            }
        }
    }
    __syncthreads();
    // ---------------- phase B: z2 = relu(z1 @ Wth2^T + bh2) ----------------
    const int bcol0 = wave * 32;
    f32x4 acc2[4][2];
#pragma unroll
    for (int i = 0; i < 4; i++)
#pragma unroll
        for (int j = 0; j < 2; j++) acc2[i][j] = (f32x4){0.f, 0.f, 0.f, 0.f};
#pragma unroll
    for (int ks = 0; ks < 256; ks += 32) {
        short8 af[4], bfr[2];
#pragma unroll
        for (int i = 0; i < 4; i++)
            af[i] = *(const short8*)&z1s[i * 16 + ln][ks + q8];
#pragma unroll
        for (int j = 0; j < 2; j++)
            bfr[j] = *(const short8*)&Wth2[(size_t)(bcol0 + j * 16 + ln) * 256 + ks + q8];
#pragma unroll
        for (int i = 0; i < 4; i++)
#pragma unroll
            for (int j = 0; j < 2; j++)
                acc2[i][j] = __builtin_amdgcn_mfma_f32_16x16x32_bf16(af[i], bfr[j], acc2[i][j], 0, 0, 0);
    }
    __syncthreads();   // all waves done reading z1s -> safe to alias as z2s
#pragma unroll
    for (int i = 0; i < 4; i++) {
#pragma unroll
        for (int j = 0; j < 2; j++) {
            int col = bcol0 + j * 16 + ln;
            float bv = bh2[col];
#pragma unroll
            for (int r = 0; r < 4; r++) {
                int row = i * 16 + qr + r;
                z2s[row][col] = bf16_rn(fmaxf(acc2[i][j][r] + bv, 0.f));
            }
        }
    }
    __syncthreads();
    // ---------------- phase C: out = sigmoid(relu(z2 @ Wth3^T + bh3) . Wh4 + bh4) ----
    const int wr0 = wave * 16;
    f32x4 acc3[4];
#pragma unroll
    for (int j = 0; j < 4; j++) acc3[j] = (f32x4){0.f, 0.f, 0.f, 0.f};
#pragma unroll
    for (int ks = 0; ks < 128; ks += 32) {
        short8 af = *(const short8*)&z2s[wr0 + ln][ks + q8];
#pragma unroll
        for (int j = 0; j < 4; j++) {
            short8 bfr = *(const short8*)&Wth3[(size_t)(j * 16 + ln) * 128 + ks + q8];
            acc3[j] = __builtin_amdgcn_mfma_f32_16x16x32_bf16(af, bfr, acc3[j], 0, 0, 0);
        }
    }
    float b3c[4], w4c[4];
#pragma unroll
    for (int j = 0; j < 4; j++) {
        b3c[j] = bh3[j * 16 + ln];
        w4c[j] = Wh4[j * 16 + ln];
    }
    float b4 = bh4[0];
    float part[4];
#pragma unroll
    for (int r = 0; r < 4; r++) {
        float s = 0.f;
#pragma unroll
        for (int j = 0; j < 4; j++)
            s = fmaf(fmaxf(acc3[j][r] + b3c[j], 0.f), w4c[j], s);
        part[r] = s;
    }
#pragma unroll
    for (int r = 0; r < 4; r++) {
        float s = part[r];
        s += __shfl_xor(s, 1); s += __shfl_xor(s, 2);
        s += __shfl_xor(s, 4); s += __shfl_xor(s, 8);
        part[r] = s;
    }
    if (ln == 0) {
#pragma unroll
        for (int r = 0; r < 4; r++)
            out[row0 + wr0 + qr + r] = 1.0f / (1.0f + expf(-(part[r] + b4)));
    }
}

// ---------------- launch ------------------------------------------------------------

extern "C" void kernel_launch(void* const* d_in, const int* in_sizes, int n_in,
                              void* d_out, int out_size, void* d_ws, size_t ws_size,
                              hipStream_t stream) {
    const float* x          = (const float*)d_in[0];
    const int*   eidx       = (const int*)d_in[1];
    const int*   esrc       = eidx;
    const int*   edst       = eidx + EE;
    const int*   origin     = (const int*)d_in[2];
    const int*   destid     = (const int*)d_in[3];
    const int*   day_ids    = (const int*)d_in[4];
    const int*   time_ids   = (const int*)d_in[5];
    const int*   mode_ids   = (const int*)d_in[6];
    const float* W1 = (const float*)d_in[7];   const float* b1 = (const float*)d_in[8];
    const float* W2 = (const float*)d_in[9];   const float* b2 = (const float*)d_in[10];
    const float* W3 = (const float*)d_in[11];  const float* b3 = (const float*)d_in[12];
    const float* day_table  = (const float*)d_in[13];
    const float* time_table = (const float*)d_in[14];
    const float* mode_table = (const float*)d_in[15];
    const float* Wf  = (const float*)d_in[16]; const float* bf  = (const float*)d_in[17];
    const float* Wh1 = (const float*)d_in[18]; const float* bh1 = (const float*)d_in[19];
    const float* Wh2 = (const float*)d_in[20]; const float* bh2 = (const float*)d_in[21];
    const float* Wh3 = (const float*)d_in[22]; const float* bh3 = (const float*)d_in[23];
    const float* Wh4 = (const float*)d_in[24]; const float* bh4 = (const float*)d_in[25];
    float* out = (float*)d_out;

    char* wsb = (char*)d_ws;
    size_t off = 0;
    auto alloc = [&](size_t bytes) -> char* {
        char* p = wsb + off;
        off = (off + bytes + 511) & ~(size_t)511;
        return p;
    };
    // zero-initialized block: bcnt | bcur0 (one memset)
    int*   zblk    = (int*)alloc((2 * NBK + 1) * 4);
    int*   bcnt    = zblk;
    int*   bcur0   = zblk + (NBK + 1);
    int*   offsets = (int*)alloc((size_t)(NN + 1) * 4);
    float* dinv    = (float*)alloc((size_t)NN * 4);
    int2*  binned  = (int2*)alloc((size_t)EE * 8);
    int*   epsrc   = (int*)alloc((size_t)EE * 4);
    unsigned short* Wt1  = (unsigned short*)alloc(128 * 128 * 2);
    unsigned short* Wt2  = (unsigned short*)alloc(128 * 128 * 2);
    unsigned short* Wt3  = (unsigned short*)alloc(128 * 128 * 2);
    unsigned short* Wtf  = (unsigned short*)alloc(128 * 128 * 2);
    unsigned short* Wth1 = (unsigned short*)alloc(256 * 256 * 2);
    unsigned short* Wth2 = (unsigned short*)alloc(128 * 256 * 2);
    unsigned short* Wth3 = (unsigned short*)alloc(64 * 128 * 2);
    float* CC = (float*)alloc(30 * 256 * 4);
    unsigned char*  bufHW = (unsigned char*)alloc((size_t)NN * 128);   // fp8 hw / h2
    unsigned char*  bufH  = (unsigned char*)alloc((size_t)NN * 128);   // fp8 h1 / h3

    hipMemsetAsync(zblk, 0, (2 * NBK + 1) * 4, stream);
    k_bcount<<<BINB, 1024, 0, stream>>>(edst, bcnt);
    k_bin<<<BINB, 1024, 0, stream>>>(esrc, edst, bcnt, bcur0, binned);
    k_boffplace<<<NBK, 256, 0, stream>>>(binned, bcnt, offsets, dinv, epsrc);

    k_wtcc<<<672 + 30, 256, 0, stream>>>(W1, W2, W3, Wf, Wh1, Wh2, Wh3,
                                         Wt1, Wt2, Wt3, Wtf, Wth1, Wth2, Wth3,
                                         day_table, time_table, mode_table, bf, bh1, CC);

    const int GB = (NN + 127) / 128;   // 782
    const int AB = (NN + 31) / 32;     // 3125 blocks, 32 nodes/block
    // L1: transform-first (x is f32, 512B rows -> gather hw fp8 instead)
    k_mfma<128, 128, 4, 0, 2, 1><<<dim3(GB, 1), 256, 0, stream>>>(x, Wt1, nullptr, bufHW, NN, 128);
    k_agg8<<<AB, 256, 0, stream>>>(bufHW, epsrc, offsets, dinv, b1, bufH);      // h1
    // L2/L3: aggregate-first (fused agg+GEMM, one fp8 quantization per layer)
    k_aggmm<<<AB, 256, 0, stream>>>(bufH, epsrc, offsets, dinv, Wt2, b2, bufHW); // h2
    k_aggmm<<<AB, 256, 0, stream>>>(bufHW, epsrc, offsets, dinv, Wt3, b3, bufH); // h3

    k_headall<<<BQ / 64, 256, 0, stream>>>(bufH, origin, destid, day_ids, time_ids,
                                           mode_ids, CC, Wth1, Wth2, Wth3,
                                           bh2, bh3, Wh4, bh4, out);
}